// Round 15
// baseline (1516.991 us; speedup 1.0000x reference)
//
#include <hip/hip_runtime.h>
#include <math.h>

#define D_  128
#define B_  8
#define H_  8
#define LC_ 512
#define LQ_ 64

typedef float f32x4 __attribute__((ext_vector_type(4)));
typedef short bf16x8 __attribute__((ext_vector_type(8)));
typedef short short4v __attribute__((ext_vector_type(4)));
typedef unsigned short ushortT;

__device__ inline short bfr(float x) {
  unsigned u = __float_as_uint(x);
  u += 0x7fff + ((u >> 16) & 1);
  return (short)(u >> 16);
}
__device__ inline float bfi(ushortT u) {
  return __uint_as_float(((unsigned)u) << 16);
}

__device__ inline bf16x8 mk8(short4v lo, short4v hi) {
  bf16x8 r;
  r[0] = lo[0]; r[1] = lo[1]; r[2] = lo[2]; r[3] = lo[3];
  r[4] = hi[0]; r[5] = hi[1]; r[6] = hi[2]; r[7] = hi[3];
  return r;
}

// A-frag: W[m=lane&15][k], k = koff + g*4 + (j&3) + 16*(j>>2)
__device__ inline bf16x8 ldA(const ushortT* row, int koff) {
  short4v lo = *(const short4v*)(row + koff);
  short4v hi = *(const short4v*)(row + koff + 16);
  return mk8(lo, hi);
}
__device__ inline bf16x8 ldB2(const ushortT* plo, const ushortT* phi) {
  short4v lo = *(const short4v*)plo;
  short4v hi = *(const short4v*)phi;
  return mk8(lo, hi);
}

// ---------------------------------------------------------------- weight prep
__global__ void k_prep(const float* a0, const float* a1, const float* a2,
                       const float* a3, const float* a4, const float* a5,
                       const float* a6, const float* a7, const float* a8,
                       const float* a9, const float* a10, ushortT* dst) {
  int i = blockIdx.x * 256 + threadIdx.x;
  if (i >= 1114112) return;
  const float* s; int lo;
  if      (i <   65536) { s = a0;  lo = i; }
  else if (i <   98304) { s = a1;  lo = i - 65536; }
  else if (i <  114688) { s = a2;  lo = i - 98304; }
  else if (i <  131072) { s = a3;  lo = i - 114688; }
  else if (i <  147456) { s = a4;  lo = i - 131072; }
  else if (i <  311296) { s = a5;  lo = i - 147456; }
  else if (i <  540672) { s = a6;  lo = i - 311296; }
  else if (i <  770048) { s = a7;  lo = i - 540672; }
  else if (i <  884736) { s = a8;  lo = i - 770048; }
  else if (i <  999424) { s = a9;  lo = i - 884736; }
  else                  { s = a10; lo = i - 999424; }
  dst[i] = (ushortT)bfr(s[lo]);
}

// pos-signal table: pos[d*512 + l]
__global__ void k_postab(float* pos) {
  int i = blockIdx.x * 256 + threadIdx.x;  // 65536
  int d = i >> 9, l = i & 511;
  int j = d & 63;
  float arg = (float)l * expf(-(float)j * 0.14619588f);
  pos[i] = (d < 64) ? sinf(arg) : cosf(arg);
}

// ---------------------------------------------------------------- fused double conv (dual C/Q)
// grid (ntC [+ntQ], 2, B), 256 thr; bx<ntC -> C tile, else Q tile.
template <int KK, int ADDPOS>
__global__ __launch_bounds__(256) void k_fusedconv(
    const float* __restrict__ xC, float* __restrict__ yC,
    const float* __restrict__ xQ, float* __restrict__ yQ,
    const float* __restrict__ pos,
    const float* __restrict__ dw1, const ushortT* __restrict__ pw1,
    const float* __restrict__ pb1, const float* __restrict__ g1,
    const float* __restrict__ be1,
    const float* __restrict__ dw2, const ushortT* __restrict__ pw2,
    const float* __restrict__ pb2, const float* __restrict__ g2w,
    const float* __restrict__ be2, int ntC) {
  const int HALO = KK / 2;
  const int W1 = 32 + 2 * HALO;
  __shared__ __align__(16) float raw[128 * 40];
  __shared__ __align__(16) ushortT l1o[128 * 36];
  __shared__ __align__(16) ushortT xbf1[32 * 32 * 4];
  __shared__ float mu1[40], rs1[40], mu2[32], rs2[32], ps[160], psq[160];
  ushortT* xbf2 = (ushortT*)raw;
  int bx = blockIdx.x;
  const float* x; float* yout; int l0, L;
  if (bx < ntC) { x = xC; yout = yC; l0 = bx * 16; L = LC_; }
  else          { x = xQ; yout = yQ; l0 = (bx - ntC) * 16; L = LQ_; }
  int o0 = blockIdx.y * 64;
  int b = blockIdx.z;
  int tid = threadIdx.x;
  for (int idx = tid; idx < 128 * W1; idx += 256) {
    int d = idx / W1, c = idx - d * W1;
    int gl = l0 - 8 - HALO + c;
    float v = 0.f;
    if (gl >= 0 && gl < L) {
      v = x[((size_t)b * 128 + d) * L + gl];
      if (ADDPOS) v += pos[d * 512 + gl];
    }
    raw[d * 40 + c] = v;
  }
  __syncthreads();
  if (tid < 4 * W1) {
    int c = tid % W1, hh = tid / W1;
    float s = 0.f, s2 = 0.f;
    for (int d = hh * 32; d < hh * 32 + 32; d++) {
      float v = raw[d * 40 + c];
      s += v; s2 += v * v;
    }
    ps[tid] = s; psq[tid] = s2;
  }
  __syncthreads();
  if (tid < W1) {
    float s = ps[tid] + ps[tid + W1] + ps[tid + 2 * W1] + ps[tid + 3 * W1];
    float s2 = psq[tid] + psq[tid + W1] + psq[tid + 2 * W1] + psq[tid + 3 * W1];
    float mu = s * (1.f / 128.f);
    float var = fmaxf(s2 * (1.f / 128.f) - mu * mu, 0.f);
    mu1[tid] = mu; rs1[tid] = rsqrtf(var + 1e-5f);
  }
  __syncthreads();
  {
    int cc0 = tid & 31, dbase = tid >> 5;
#pragma unroll
    for (int kq = 0; kq < 4; kq++) {
      short4v pk;
#pragma unroll
      for (int e = 0; e < 4; e++) {
        int d = dbase * 16 + kq * 4 + e;
        float gg = g1[d], bb = be1[d];
        const float* wr = dw1 + d * KK;
        float acc = 0.f;
#pragma unroll
        for (int t = 0; t < KK; t++) {
          int ci = cc0 + t;
          int gl = l0 - 8 - HALO + ci;
          float lv = 0.f;
          if (gl >= 0 && gl < L)
            lv = (raw[d * 40 + ci] - mu1[ci]) * rs1[ci] * gg + bb;
          acc += wr[t] * lv;
        }
        pk[e] = bfr(acc);
      }
      *(short4v*)&xbf1[(((dbase * 4 + kq) * 32) + cc0) * 4] = pk;
    }
  }
  __syncthreads();
  int w = tid >> 6, lane = tid & 63, g2 = lane >> 4, r = lane & 15;
  {
    f32x4 acc[2][2];
#pragma unroll
    for (int i = 0; i < 2; i++)
#pragma unroll
      for (int nt = 0; nt < 2; nt++) acc[i][nt] = (f32x4){0.f, 0.f, 0.f, 0.f};
#pragma unroll
    for (int i = 0; i < 2; i++) {
      const ushortT* arow = pw1 + (size_t)((2 * w + i) * 16 + r) * 128;
#pragma unroll
      for (int kk = 0; kk < 4; kk++) {
        bf16x8 a = ldA(arow, kk * 32 + g2 * 4);
#pragma unroll
        for (int nt = 0; nt < 2; nt++) {
          bf16x8 bb = ldB2(&xbf1[(((kk * 8 + g2) * 32) + nt * 16 + r) * 4],
                           &xbf1[(((kk * 8 + 4 + g2) * 32) + nt * 16 + r) * 4]);
          acc[i][nt] = __builtin_amdgcn_mfma_f32_16x16x32_bf16(a, bb, acc[i][nt], 0, 0, 0);
        }
      }
    }
#pragma unroll
    for (int i = 0; i < 2; i++)
#pragma unroll
      for (int nt = 0; nt < 2; nt++)
#pragma unroll
        for (int p = 0; p < 4; p++) {
          int o = (2 * w + i) * 16 + g2 * 4 + p;
          int c1 = nt * 16 + r;
          int gl = l0 - 8 + c1;
          float val = 0.f;
          if (gl >= 0 && gl < L)
            val = fmaxf(acc[i][nt][p] + pb1[o], 0.f) + raw[o * 40 + c1 + HALO];
          l1o[o * 36 + c1] = (ushortT)bfr(val);
        }
  }
  __syncthreads();
  if (tid < 128) {
    int c = tid & 31, hh = tid >> 5;
    float s = 0.f, s2 = 0.f;
    for (int d = hh * 32; d < hh * 32 + 32; d++) {
      float v = bfi(l1o[d * 36 + c]);
      s += v; s2 += v * v;
    }
    ps[tid] = s; psq[tid] = s2;
  }
  __syncthreads();
  if (tid < 32) {
    float s = ps[tid] + ps[tid + 32] + ps[tid + 64] + ps[tid + 96];
    float s2 = psq[tid] + psq[tid + 32] + psq[tid + 64] + psq[tid + 96];
    float mu = s * (1.f / 128.f);
    float var = fmaxf(s2 * (1.f / 128.f) - mu * mu, 0.f);
    mu2[tid] = mu; rs2[tid] = rsqrtf(var + 1e-5f);
  }
  __syncthreads();
  {
    int cc2 = tid & 15, db2 = tid >> 4;
#pragma unroll
    for (int kq = 0; kq < 2; kq++) {
      short4v pk;
#pragma unroll
      for (int e = 0; e < 4; e++) {
        int d = db2 * 8 + kq * 4 + e;
        float gg = g2w[d], bb = be2[d];
        const float* wr = dw2 + d * KK;
        float acc = 0.f;
#pragma unroll
        for (int t = 0; t < KK; t++) {
          int c1 = cc2 + 8 + t - HALO;
          int gl = l0 + cc2 + t - HALO;
          float lv = 0.f;
          if (gl >= 0 && gl < L)
            lv = (bfi(l1o[d * 36 + c1]) - mu2[c1]) * rs2[c1] * gg + bb;
          acc += wr[t] * lv;
        }
        pk[e] = bfr(acc);
      }
      *(short4v*)&xbf2[(((db2 * 2 + kq) * 16) + cc2) * 4] = pk;
    }
  }
  __syncthreads();
  {
    f32x4 a2 = {0.f, 0.f, 0.f, 0.f};
    const ushortT* arow = pw2 + (size_t)(o0 + 16 * w + r) * 128;
#pragma unroll
    for (int kk = 0; kk < 4; kk++) {
      bf16x8 a = ldA(arow, kk * 32 + g2 * 4);
      bf16x8 bb = ldB2(&xbf2[(((kk * 8 + g2) * 16) + r) * 4],
                       &xbf2[(((kk * 8 + 4 + g2) * 16) + r) * 4]);
      a2 = __builtin_amdgcn_mfma_f32_16x16x32_bf16(a, bb, a2, 0, 0, 0);
    }
#pragma unroll
    for (int p = 0; p < 4; p++) {
      int o = o0 + 16 * w + g2 * 4 + p;
      yout[((size_t)b * 128 + o) * L + l0 + r] =
          fmaxf(a2[p] + pb2[o], 0.f) + bfi(l1o[o * 36 + 8 + r]);
    }
  }
}

// ---------------------------------------------------------------- LN1 + projections only (model encoder)
// grid (32, 1, B), 512 thr. Reads x (fp32), writes bf16 mkv/qp. 3 barriers.
__global__ __launch_bounds__(512) void k_proj(
    const float* __restrict__ x, const ushortT* __restrict__ memw,
    const ushortT* __restrict__ qw, const float* __restrict__ g3,
    const float* __restrict__ be3, ushortT* __restrict__ mkv,
    ushortT* __restrict__ qp) {
  __shared__ float xs[128 * 16];
  __shared__ __align__(16) ushortT xbf3[128 * 16];
  __shared__ float mu_s[16], rs_s[16], ps[512], psq[512];
  int l0 = blockIdx.x * 16;
  int b = blockIdx.z;
  int tid = threadIdx.x;
  {
    int c = tid & 15, hh = tid >> 4;   // hh 0..31, 4 ch each
    float s = 0.f, s2 = 0.f;
#pragma unroll
    for (int e = 0; e < 4; e++) {
      int d = hh * 4 + e;
      float v = x[((size_t)b * 128 + d) * LC_ + l0 + c];
      xs[d * 16 + c] = v;
      s += v; s2 += v * v;
    }
    ps[tid] = s; psq[tid] = s2;
  }
  __syncthreads();
  if (tid < 16) {
    float s = 0.f, s2 = 0.f;
#pragma unroll
    for (int hh = 0; hh < 32; hh++) { s += ps[hh * 16 + tid]; s2 += psq[hh * 16 + tid]; }
    float mu = s * (1.f / 128.f);
    float var = fmaxf(s2 * (1.f / 128.f) - mu * mu, 0.f);
    mu_s[tid] = mu; rs_s[tid] = rsqrtf(var + 1e-5f);
  }
  __syncthreads();
  for (int idx = tid; idx < 2048; idx += 512) {
    int d = idx >> 4, c = idx & 15;
    float val = (xs[d * 16 + c] - mu_s[c]) * rs_s[c] * g3[d] + be3[d];
    xbf3[(((d >> 2) * 16) + c) * 4 + (d & 3)] = (ushortT)bfr(val);
  }
  __syncthreads();
  int w = tid >> 6, lane = tid & 63, g2 = lane >> 4, r = lane & 15;
#pragma unroll
  for (int t = 0; t < 3; t++) {
    int mt = w + 8 * t;
    const ushortT* arow; ushortT* outp; int obase, O;
    if (mt < 16) { arow = memw + (size_t)(mt * 16 + r) * 128; outp = mkv; obase = mt * 16; O = 256; }
    else         { arow = qw + (size_t)((mt - 16) * 16 + r) * 128; outp = qp; obase = (mt - 16) * 16; O = 128; }
    f32x4 acc = {0.f, 0.f, 0.f, 0.f};
#pragma unroll
    for (int kk = 0; kk < 4; kk++) {
      bf16x8 a = ldA(arow, kk * 32 + g2 * 4);
      bf16x8 bb = ldB2(&xbf3[(((kk * 8 + g2) * 16) + r) * 4],
                       &xbf3[(((kk * 8 + 4 + g2) * 16) + r) * 4]);
      acc = __builtin_amdgcn_mfma_f32_16x16x32_bf16(a, bb, acc, 0, 0, 0);
    }
#pragma unroll
    for (int p = 0; p < 4; p++)
      outp[((size_t)b * O + obase + g2 * 4 + p) * LC_ + l0 + r] = (ushortT)bfr(acc[p]);
  }
}

// ---------------------------------------------------------------- conv pair + LN1 + projections (input encoders, dual C/Q)
template <int KK, int ADDPOS>
__global__ __launch_bounds__(1024) void k_convproj1024(
    const float* __restrict__ xC, float* __restrict__ yC,
    ushortT* __restrict__ mkvC, ushortT* __restrict__ qpC,
    const float* __restrict__ xQ, float* __restrict__ yQ,
    ushortT* __restrict__ mkvQ, ushortT* __restrict__ qpQ,
    const float* __restrict__ pos,
    const float* __restrict__ dw1, const ushortT* __restrict__ pw1,
    const float* __restrict__ pb1, const float* __restrict__ g1,
    const float* __restrict__ be1,
    const float* __restrict__ dw2, const ushortT* __restrict__ pw2,
    const float* __restrict__ pb2, const float* __restrict__ g2w,
    const float* __restrict__ be2,
    const ushortT* __restrict__ memw, const ushortT* __restrict__ qw,
    const float* __restrict__ g3, const float* __restrict__ be3, int ntC) {
  const int HALO = KK / 2;
  const int W1 = 32 + 2 * HALO;
  __shared__ __align__(16) float raw[128 * 40];
  __shared__ __align__(16) ushortT l1o[128 * 36];
  __shared__ __align__(16) ushortT xbf1[32 * 32 * 4];
  __shared__ __align__(16) ushortT c2o[128 * 16];
  __shared__ float mu1[40], rs1[40], mu2[32], rs2[32], mu3[16], rs3[16];
  __shared__ float ps[160], psq[160];
  ushortT* xbf2 = (ushortT*)raw;
  ushortT* xbf3 = (ushortT*)(raw + 4096);
  int bx = blockIdx.x;
  const float* x; float* yout; ushortT* mkv; ushortT* qp; int l0, L;
  if (bx < ntC) { x = xC; yout = yC; mkv = mkvC; qp = qpC; l0 = bx * 16; L = LC_; }
  else          { x = xQ; yout = yQ; mkv = mkvQ; qp = qpQ; l0 = (bx - ntC) * 16; L = LQ_; }
  int b = blockIdx.z;
  int tid = threadIdx.x;
  for (int idx = tid; idx < 128 * W1; idx += 1024) {
    int d = idx / W1, c = idx - d * W1;
    int gl = l0 - 8 - HALO + c;
    float v = 0.f;
    if (gl >= 0 && gl < L) {
      v = x[((size_t)b * 128 + d) * L + gl];
      if (ADDPOS) v += pos[d * 512 + gl];
    }
    raw[d * 40 + c] = v;
  }
  __syncthreads();
  if (tid < 4 * W1) {
    int c = tid % W1, hh = tid / W1;
    float s = 0.f, s2 = 0.f;
    for (int d = hh * 32; d < hh * 32 + 32; d++) {
      float v = raw[d * 40 + c];
      s += v; s2 += v * v;
    }
    ps[tid] = s; psq[tid] = s2;
  }
  __syncthreads();
  if (tid < W1) {
    float s = ps[tid] + ps[tid + W1] + ps[tid + 2 * W1] + ps[tid + 3 * W1];
    float s2 = psq[tid] + psq[tid + W1] + psq[tid + 2 * W1] + psq[tid + 3 * W1];
    float mu = s * (1.f / 128.f);
    float var = fmaxf(s2 * (1.f / 128.f) - mu * mu, 0.f);
    mu1[tid] = mu; rs1[tid] = rsqrtf(var + 1e-5f);
  }
  __syncthreads();
  {
    int cc0 = tid & 31, dbase = tid >> 5;
    short4v pk;
#pragma unroll
    for (int e = 0; e < 4; e++) {
      int d = dbase * 4 + e;
      float gg = g1[d], bb = be1[d];
      const float* wr = dw1 + d * KK;
      float acc = 0.f;
#pragma unroll
      for (int t = 0; t < KK; t++) {
        int ci = cc0 + t;
        int gl = l0 - 8 - HALO + ci;
        float lv = 0.f;
        if (gl >= 0 && gl < L)
          lv = (raw[d * 40 + ci] - mu1[ci]) * rs1[ci] * gg + bb;
        acc += wr[t] * lv;
      }
      pk[e] = bfr(acc);
    }
    *(short4v*)&xbf1[((dbase * 32) + cc0) * 4] = pk;
  }
  __syncthreads();
  int w = tid >> 6, lane = tid & 63, g2 = lane >> 4, r = lane & 15;
  {
    int m = w & 7, nt = w >> 3;
    f32x4 acc = {0.f, 0.f, 0.f, 0.f};
    const ushortT* arow = pw1 + (size_t)(m * 16 + r) * 128;
#pragma unroll
    for (int kk = 0; kk < 4; kk++) {
      bf16x8 a = ldA(arow, kk * 32 + g2 * 4);
      bf16x8 bb = ldB2(&xbf1[(((kk * 8 + g2) * 32) + nt * 16 + r) * 4],
                       &xbf1[(((kk * 8 + 4 + g2) * 32) + nt * 16 + r) * 4]);
      acc = __builtin_amdgcn_mfma_f32_16x16x32_bf16(a, bb, acc, 0, 0, 0);
    }
#pragma unroll
    for (int p = 0; p < 4; p++) {
      int o = m * 16 + g2 * 4 + p;
      int c1 = nt * 16 + r;
      int gl = l0 - 8 + c1;
      float val = 0.f;
      if (gl >= 0 && gl < L)
        val = fmaxf(acc[p] + pb1[o], 0.f) + raw[o * 40 + c1 + HALO];
      l1o[o * 36 + c1] = (ushortT)bfr(val);
    }
  }
  __syncthreads();
  if (tid < 128) {
    int c = tid & 31, hh = tid >> 5;
    float s = 0.f, s2 = 0.f;
    for (int d = hh * 32; d < hh * 32 + 32; d++) {
      float v = bfi(l1o[d * 36 + c]);
      s += v; s2 += v * v;
    }
    ps[tid] = s; psq[tid] = s2;
  }
  __syncthreads();
  if (tid < 32) {
    float s = ps[tid] + ps[tid + 32] + ps[tid + 64] + ps[tid + 96];
    float s2 = psq[tid] + psq[tid + 32] + psq[tid + 64] + psq[tid + 96];
    float mu = s * (1.f / 128.f);
    float var = fmaxf(s2 * (1.f / 128.f) - mu * mu, 0.f);
    mu2[tid] = mu; rs2[tid] = rsqrtf(var + 1e-5f);
  }
  __syncthreads();
  {
    int cc2 = tid & 15, db2 = tid >> 4;
#pragma unroll
    for (int e = 0; e < 2; e++) {
      int d = db2 * 2 + e;
      float gg = g2w[d], bb = be2[d];
      const float* wr = dw2 + d * KK;
      float acc = 0.f;
#pragma unroll
      for (int t = 0; t < KK; t++) {
        int c1 = cc2 + 8 + t - HALO;
        int gl = l0 + cc2 + t - HALO;
        float lv = 0.f;
        if (gl >= 0 && gl < L)
          lv = (bfi(l1o[d * 36 + c1]) - mu2[c1]) * rs2[c1] * gg + bb;
        acc += wr[t] * lv;
      }
      xbf2[(((d >> 2) * 16) + cc2) * 4 + (d & 3)] = (ushortT)bfr(acc);
    }
  }
  __syncthreads();
  if (w < 8) {
    f32x4 a2 = {0.f, 0.f, 0.f, 0.f};
    const ushortT* arow = pw2 + (size_t)(w * 16 + r) * 128;
#pragma unroll
    for (int kk = 0; kk < 4; kk++) {
      bf16x8 a = ldA(arow, kk * 32 + g2 * 4);
      bf16x8 bb = ldB2(&xbf2[(((kk * 8 + g2) * 16) + r) * 4],
                       &xbf2[(((kk * 8 + 4 + g2) * 16) + r) * 4]);
      a2 = __builtin_amdgcn_mfma_f32_16x16x32_bf16(a, bb, a2, 0, 0, 0);
    }
#pragma unroll
    for (int p = 0; p < 4; p++) {
      int o = w * 16 + g2 * 4 + p;
      float val = fmaxf(a2[p] + pb2[o], 0.f) + bfi(l1o[o * 36 + 8 + r]);
      yout[((size_t)b * 128 + o) * L + l0 + r] = val;
      c2o[o * 16 + r] = (ushortT)bfr(val);
    }
  }
  __syncthreads();
  if (tid < 128) {
    int c = tid & 15, hh = tid >> 4;
    float s = 0.f, s2 = 0.f;
    for (int d = hh * 16; d < hh * 16 + 16; d++) {
      float v = bfi(c2o[d * 16 + c]);
      s += v; s2 += v * v;
    }
    ps[tid] = s; psq[tid] = s2;
  }
  __syncthreads();
  if (tid < 16) {
    float s = 0.f, s2 = 0.f;
#pragma unroll
    for (int hh = 0; hh < 8; hh++) { s += ps[hh * 16 + tid]; s2 += psq[hh * 16 + tid]; }
    float mu = s * (1.f / 128.f);
    float var = fmaxf(s2 * (1.f / 128.f) - mu * mu, 0.f);
    mu3[tid] = mu; rs3[tid] = rsqrtf(var + 1e-5f);
  }
  __syncthreads();
  for (int idx = tid; idx < 2048; idx += 1024) {
    int d = idx >> 4, c = idx & 15;
    float val = (bfi(c2o[d * 16 + c]) - mu3[c]) * rs3[c] * g3[d] + be3[d];
    xbf3[(((d >> 2) * 16) + c) * 4 + (d & 3)] = (ushortT)bfr(val);
  }
  __syncthreads();
#pragma unroll
  for (int t = 0; t < 2; t++) {
    int mt = w + 16 * t;
    if (mt < 24) {
      const ushortT* arow; ushortT* outp; int obase, O;
      if (mt < 16) { arow = memw + (size_t)(mt * 16 + r) * 128; outp = mkv; obase = mt * 16; O = 256; }
      else         { arow = qw + (size_t)((mt - 16) * 16 + r) * 128; outp = qp; obase = (mt - 16) * 16; O = 128; }
      f32x4 acc = {0.f, 0.f, 0.f, 0.f};
#pragma unroll
      for (int kk = 0; kk < 4; kk++) {
        bf16x8 a = ldA(arow, kk * 32 + g2 * 4);
        bf16x8 bb = ldB2(&xbf3[(((kk * 8 + g2) * 16) + r) * 4],
                         &xbf3[(((kk * 8 + 4 + g2) * 16) + r) * 4]);
        acc = __builtin_amdgcn_mfma_f32_16x16x32_bf16(a, bb, acc, 0, 0, 0);
      }
#pragma unroll
      for (int p = 0; p < 4; p++)
        outp[((size_t)b * O + obase + g2 * 4 + p) * L + l0 + r] = (ushortT)bfr(acc[p]);
    }
  }
}

// ---------------------------------------------------------------- attention + LN2 + FFN body (bf16 K/V/Q, 1024 thr)
template <int NCH, int WOUT>
__device__ __forceinline__ void attn_body(
    char* smem, const ushortT* memKV, const ushortT* qp, const float* mask,
    float* cur, const ushortT* w1bf, const float* b1,
    const ushortT* w2bf, const float* b2,
    const float* g, const float* be, float* wout, int q0, int b, int L, int tid) {
  float* msh = (float*)smem;
  float* ssh = (float*)(smem + 2048);
  float* OshF = (float*)(smem + 4096);
  float* updT = (float*)(smem + 12288);
  ushortT* xbf = (ushortT*)(smem + 20480);
  ushortT* midbf = (ushortT*)(smem + 24576);
  float* mu_s = (float*)(smem + 28672);
  float* rs_s = (float*)(smem + 28736);
  float* ps = (float*)(smem + 28800);
  float* psq = (float*)(smem + 32896);
  int w = tid >> 6;
  int h = w & 7, kh = w >> 3;
  int lane = tid & 63;
  int g2 = lane >> 4, r = lane & 15;
  const ushortT* qb = qp + ((size_t)b * 128 + h * 16) * L;
  const ushortT* kb = memKV + ((size_t)b * 256 + h * 16) * L;
  const ushortT* vb = memKV + ((size_t)b * 256 + 128 + h * 16) * L;
  const float* mk = mask + (size_t)b * L;
  int qcol = q0 + r;
  bf16x8 qf;
#pragma unroll
  for (int j = 0; j < 4; j++)
    qf[j] = bfr(bfi(qb[(size_t)(g2 * 4 + j) * L + qcol]) * 0.25f);
  qf[4] = 0; qf[5] = 0; qf[6] = 0; qf[7] = 0;
  float m_run = -INFINITY, ssum = 0.f;
  f32x4 O = {0.f, 0.f, 0.f, 0.f};
  int kbeg = kh * (L / 2), kend = (kh + 1) * (L / 2);
  for (int k0 = kbeg; k0 < kend; k0 += NCH * 16) {
    f32x4 sd[NCH];
#pragma unroll
    for (int mc = 0; mc < NCH; mc++) {
      bf16x8 kf;
      int krow = k0 + mc * 16 + r;
#pragma unroll
      for (int j = 0; j < 4; j++)
        kf[j] = (short)kb[(size_t)(g2 * 4 + j) * L + krow];
      kf[4] = 0; kf[5] = 0; kf[6] = 0; kf[7] = 0;
      f32x4 z = {0.f, 0.f, 0.f, 0.f};
      sd[mc] = __builtin_amdgcn_mfma_f32_16x16x32_bf16(kf, qf, z, 0, 0, 0);
    }
    float tm = -INFINITY;
#pragma unroll
    for (int mc = 0; mc < NCH; mc++) {
#pragma unroll
      for (int p = 0; p < 4; p++) {
        float mv = mk[k0 + mc * 16 + g2 * 4 + p];
        float sv = sd[mc][p] * mv + (1.f - mv) * (-1e30f);
        sd[mc][p] = sv;
        tm = fmaxf(tm, sv);
      }
    }
    tm = fmaxf(tm, __shfl_xor(tm, 16));
    tm = fmaxf(tm, __shfl_xor(tm, 32));
    float nm = fmaxf(m_run, tm);
    float c = __expf(m_run - nm);
    ssum *= c;
    O[0] *= c; O[1] *= c; O[2] *= c; O[3] *= c;
    float psum = 0.f;
    bf16x8 pf[NCH / 2];
#pragma unroll
    for (int c2 = 0; c2 < NCH / 2; c2++) {
#pragma unroll
      for (int j = 0; j < 4; j++) {
        float e0 = __expf(sd[2 * c2][j] - nm);
        float e1 = __expf(sd[2 * c2 + 1][j] - nm);
        psum += e0 + e1;
        pf[c2][j] = bfr(e0);
        pf[c2][j + 4] = bfr(e1);
      }
    }
    psum += __shfl_xor(psum, 16);
    psum += __shfl_xor(psum, 32);
    ssum += psum;
#pragma unroll
    for (int c2 = 0; c2 < NCH / 2; c2++) {
      const ushortT* vrow = vb + (size_t)r * L + k0 + c2 * 32 + g2 * 4;
      short4v lo = *(const short4v*)vrow;
      short4v hi = *(const short4v*)(vrow + 16);
      bf16x8 vf = mk8(lo, hi);
      O = __builtin_amdgcn_mfma_f32_16x16x32_bf16(vf, pf[c2], O, 0, 0, 0);
    }
    m_run = nm;
  }
  if (kh == 1) {
    msh[h * 64 + lane] = m_run;
    ssh[h * 64 + lane] = ssum;
#pragma unroll
    for (int p = 0; p < 4; p++) OshF[(h * 64 + lane) * 4 + p] = O[p];
  }
  __syncthreads();
  if (kh == 0) {
    float mB = msh[h * 64 + lane], sB = ssh[h * 64 + lane];
    float nm = fmaxf(m_run, mB);
    float cA = __expf(m_run - nm), cB = __expf(mB - nm);
    float inv = 1.f / (ssum * cA + sB * cB);
#pragma unroll
    for (int p = 0; p < 4; p++) {
      int d = h * 16 + g2 * 4 + p;
      float ov = (O[p] * cA + OshF[(h * 64 + lane) * 4 + p] * cB) * inv;
      updT[d * 16 + r] = cur[((size_t)b * 128 + d) * L + qcol] + ov;
    }
  }
  __syncthreads();
  {
    int c = tid & 15, hh = tid >> 4;
    float s = 0.f, s2 = 0.f;
    for (int d = hh * 2; d < hh * 2 + 2; d++) {
      float v = updT[d * 16 + c];
      s += v; s2 += v * v;
    }
    ps[tid] = s; psq[tid] = s2;
  }
  __syncthreads();
  if (tid < 16) {
    float s = 0.f, s2 = 0.f;
    for (int hh = 0; hh < 64; hh++) { s += ps[hh * 16 + tid]; s2 += psq[hh * 16 + tid]; }
    float mu = s * (1.f / 128.f);
    float var = fmaxf(s2 * (1.f / 128.f) - mu * mu, 0.f);
    mu_s[tid] = mu; rs_s[tid] = rsqrtf(var + 1e-5f);
  }
  __syncthreads();
  for (int idx = tid; idx < 2048; idx += 1024) {
    int d = idx >> 4, c = idx & 15;
    float val = (updT[d * 16 + c] - mu_s[c]) * rs_s[c] * g[d] + be[d];
    xbf[(((d >> 2) * 16) + c) * 4 + (d & 3)] = (ushortT)bfr(val);
  }
  __syncthreads();
  int w8 = tid >> 6;
  int g2b = (tid & 63) >> 4, rb = tid & 15;
  if (w8 < 8) {
    f32x4 acc = {0.f, 0.f, 0.f, 0.f};
    const ushortT* ar = w1bf + (size_t)(16 * w8 + rb) * 128;
#pragma unroll
    for (int kk = 0; kk < 4; kk++) {
      bf16x8 a = ldA(ar, kk * 32 + g2b * 4);
      bf16x8 bb = ldB2(&xbf[(((kk * 8 + g2b) * 16) + rb) * 4],
                       &xbf[(((kk * 8 + 4 + g2b) * 16) + rb) * 4]);
      acc = __builtin_amdgcn_mfma_f32_16x16x32_bf16(a, bb, acc, 0, 0, 0);
    }
#pragma unroll
    for (int p = 0; p < 4; p++) {
      int dmid = 16 * w8 + g2b * 4 + p;
      float val = fmaxf(acc[p] + b1[dmid], 0.f);
      midbf[(((4 * w8 + g2b) * 16) + rb) * 4 + p] = (ushortT)bfr(val);
    }
  }
  __syncthreads();
  if (w8 < 8) {
    f32x4 a2 = {0.f, 0.f, 0.f, 0.f};
    const ushortT* ar = w2bf + (size_t)(16 * w8 + rb) * 128;
#pragma unroll
    for (int kk = 0; kk < 4; kk++) {
      bf16x8 a = ldA(ar, kk * 32 + g2b * 4);
      bf16x8 bb = ldB2(&midbf[(((kk * 8 + g2b) * 16) + rb) * 4],
                       &midbf[(((kk * 8 + 4 + g2b) * 16) + rb) * 4]);
      a2 = __builtin_amdgcn_mfma_f32_16x16x32_bf16(a, bb, a2, 0, 0, 0);
    }
#pragma unroll
    for (int p = 0; p < 4; p++) {
      int o = 16 * w8 + g2b * 4 + p;
      size_t pos2 = ((size_t)b * 128 + o) * L + q0 + rb;
      float val = a2[p] + b2[o] + updT[o * 16 + rb];
      cur[pos2] = val;
      if (WOUT) wout[pos2] = val;
    }
  }
}

// model-encoder wrapper
template <int WOUT>
__global__ __launch_bounds__(1024) void k_attnffn_m(
    const ushortT* memKV, const ushortT* qp, const float* mask, float* cur,
    const ushortT* w1bf, const float* b1, const ushortT* w2bf, const float* b2,
    const float* g, const float* be, float* wout) {
  __shared__ __align__(16) char smem[36992];
  attn_body<8, WOUT>(smem, memKV, qp, mask, cur, w1bf, b1, w2bf, b2, g, be,
                     wout, blockIdx.x * 16, blockIdx.z, LC_, threadIdx.x);
}

// merged input-encoder wrapper
__global__ __launch_bounds__(1024) void k_attnffn_in(
    const ushortT* mkvC, const ushortT* qpC, const float* maskC, float* curC,
    const ushortT* mkvQ, const ushortT* qpQ, const float* maskQ, float* curQ,
    const ushortT* w1bf, const float* b1, const ushortT* w2bf, const float* b2,
    const float* g, const float* be, int ntC) {
  __shared__ __align__(16) char smem[36992];
  int bx = blockIdx.x;
  if (bx < ntC)
    attn_body<8, 0>(smem, mkvC, qpC, maskC, curC, w1bf, b1, w2bf, b2, g, be,
                    nullptr, bx * 16, blockIdx.z, LC_, threadIdx.x);
  else
    attn_body<2, 0>(smem, mkvQ, qpQ, maskQ, curQ, w1bf, b1, w2bf, b2, g, be,
                    nullptr, (bx - ntC) * 16, blockIdx.z, LQ_, threadIdx.x);
}

// ---------------------------------------------------------------- CQ section

__global__ void k_concat2m(const float* __restrict__ x1C, const float* __restrict__ x2C,
                           float* __restrict__ outC,
                           const float* __restrict__ x1Q, const float* __restrict__ x2Q,
                           float* __restrict__ outQ) {
  int idx = blockIdx.x * 256 + threadIdx.x;
  const int tot1 = B_ * 256 * LC_;
  const int tot2 = B_ * 256 * LQ_;
  if (idx < tot1) {
    int l = idx % LC_;
    int c = (idx / LC_) & 255;
    int b = idx / (LC_ * 256);
    float v = (c < 128) ? x1C[((size_t)b * 128 + c) * LC_ + l]
                        : x2C[((size_t)b * 128 + (c - 128)) * LC_ + l];
    outC[idx] = v;
  } else {
    int i2 = idx - tot1;
    if (i2 < tot2) {
      int l = i2 % LQ_;
      int c = (i2 / LQ_) & 255;
      int b = i2 / (LQ_ * 256);
      float v = (c < 128) ? x1Q[((size_t)b * 128 + c) * LQ_ + l]
                          : x2Q[((size_t)b * 128 + (c - 128)) * LQ_ + l];
      outQ[i2] = v;
    }
  }
}

__global__ void k_cqSrow(const float* __restrict__ Ce, const float* __restrict__ Qe,
                         const float* __restrict__ w4C, const float* __restrict__ w4Q,
                         const float* __restrict__ w4mlu, const float* __restrict__ cqb,
                         const float* __restrict__ qmask,
                         float* __restrict__ S, float* __restrict__ S1) {
  int idx = blockIdx.x * 256 + threadIdx.x;
  int q = idx & 63;
  int l = (idx >> 6) % LC_;
  int b = (idx >> 6) / LC_;
  const float* ce = Ce + (size_t)b * 256 * LC_ + l;
  const float* qe = Qe + (size_t)b * 256 * LQ_ + q;
  float acc = 0.f, a0 = 0.f, a1 = 0.f;
#pragma unroll 8
  for (int j = 0; j < 256; j++) {
    float cv = ce[(size_t)j * LC_];
    float qv = qe[(size_t)j * LQ_];
    acc += cv * w4mlu[j] * qv;
    a0 += cv * w4C[j];
    a1 += qv * w4Q[j];
  }
  float sv = acc + a0 + a1 + cqb[0];
  S[idx] = sv;
  float mv = qmask[b * LQ_ + q];
  float v = sv * mv + (1.f - mv) * (-1e30f);
  float mx = v;
  for (int off = 32; off; off >>= 1) mx = fmaxf(mx, __shfl_xor(mx, off));
  float p = expf(v - mx);
  float s = p;
  for (int off = 32; off; off >>= 1) s += __shfl_xor(s, off);
  S1[idx] = p / s;
}

__global__ __launch_bounds__(256) void k_softmax_col(
    const float* __restrict__ S, const float* __restrict__ cmask, float* __restrict__ S2) {
  int q = blockIdx.x & 63, b = blockIdx.x >> 6;
  int tid = threadIdx.x;
  __shared__ float redm[4], reds[4];
  const float* col = S + (size_t)b * LC_ * LQ_ + q;
  const float* mk = cmask + b * LC_;
  float vm[2];
#pragma unroll
  for (int k = 0; k < 2; k++) {
    int l = tid + 256 * k;
    float mv = mk[l];
    vm[k] = col[(size_t)l * LQ_] * mv + (1.f - mv) * (-1e30f);
  }
  float mx = fmaxf(vm[0], vm[1]);
  for (int off = 32; off; off >>= 1) mx = fmaxf(mx, __shfl_xor(mx, off));
  if ((tid & 63) == 0) redm[tid >> 6] = mx;
  __syncthreads();
  mx = fmaxf(fmaxf(redm[0], redm[1]), fmaxf(redm[2], redm[3]));
  float e0 = expf(vm[0] - mx), e1 = expf(vm[1] - mx);
  float s = e0 + e1;
  for (int off = 32; off; off >>= 1) s += __shfl_xor(s, off);
  if ((tid & 63) == 0) reds[tid >> 6] = s;
  __syncthreads();
  float invs = 1.f / (reds[0] + reds[1] + reds[2] + reds[3]);
  float* out = S2 + (size_t)b * LC_ * LQ_ + q;
  out[(size_t)tid * LQ_] = e0 * invs;
  out[(size_t)(tid + 256) * LQ_] = e1 * invs;
}

__global__ void k_cqY(const float* __restrict__ S2, const float* __restrict__ Ce,
                      float* __restrict__ Y) {
  int idx = blockIdx.x * 256 + threadIdx.x;
  if (idx >= B_ * 256 * LQ_) return;
  int q = idx & 63;
  int j = (idx >> 6) & 255;
  int b = idx >> 14;
  const float* s2 = S2 + (size_t)b * LC_ * LQ_ + q;
  const float* ce = Ce + ((size_t)b * 256 + j) * LC_;
  float acc = 0.f;
#pragma unroll 8
  for (int l = 0; l < LC_; l++) acc += s2[(size_t)l * LQ_] * ce[l];
  Y[idx] = acc;
}

__global__ __launch_bounds__(256) void k_cqAB(
    const float* __restrict__ S1, const float* __restrict__ Qe, const float* __restrict__ Y,
    float* __restrict__ A, float* __restrict__ Bt) {
  __shared__ float s1s[64][65];
  int l0 = blockIdx.x * 64;
  int b = blockIdx.z;
  int tid = threadIdx.x;
  for (int idx = tid; idx < 64 * 64; idx += 256) {
    int l = idx >> 6, q = idx & 63;
    s1s[l][q] = S1[((size_t)b * LC_ + l0 + l) * LQ_ + q];
  }
  __syncthreads();
  int ll = tid & 63, jj = tid >> 6;
  int j = blockIdx.y * 4 + jj;
  const float* qe = Qe + ((size_t)b * 256 + j) * LQ_;
  const float* yb = Y + ((size_t)b * 256 + j) * LQ_;
  float a = 0.f, bt = 0.f;
#pragma unroll 8
  for (int q = 0; q < 64; q++) {
    float sv = s1s[ll][q];
    a += sv * qe[q];
    bt += sv * yb[q];
  }
  A[((size_t)b * 256 + j) * LC_ + l0 + ll] = a;
  Bt[((size_t)b * 256 + j) * LC_ + l0 + ll] = bt;
}

__global__ __launch_bounds__(512) void k_resizer512(
    const float* __restrict__ Ce, const float* __restrict__ A,
    const float* __restrict__ Bt, const ushortT* __restrict__ wbf,
    float* __restrict__ y) {
  __shared__ __align__(16) ushortT xbf[32 * 16 * 4];
  int l0 = blockIdx.x * 16;
  int b = blockIdx.z;
  int tid = threadIdx.x;
  int w = tid >> 6, lane = tid & 63, g2 = lane >> 4, r = lane & 15;
  const ushortT* arow = wbf + (size_t)(16 * w + r) * 1280;
  f32x4 acc = {0.f, 0.f, 0.f, 0.f};
  for (int kt = 0; kt < 1280; kt += 128) {
    __syncthreads();
    for (int idx = tid; idx < 2048; idx += 512) {
      int kl = idx >> 4, cc = idx & 15;
      int ch = kt + kl;
      int seg = ch >> 8;
      int j = ch & 255;
      size_t p = ((size_t)b * 256 + j) * LC_ + l0 + cc;
      float v;
      if (seg == 0 || seg == 4) v = Ce[p];
      else if (seg == 1) v = A[p];
      else if (seg == 2) v = Ce[p] * A[p];
      else v = Ce[p] * Bt[p];
      xbf[((kl >> 2) * 16 + cc) * 4 + (kl & 3)] = (ushortT)bfr(v);
    }
    __syncthreads();
#pragma unroll
    for (int kk2 = 0; kk2 < 4; kk2++) {
      bf16x8 a = ldA(arow, kt + kk2 * 32 + g2 * 4);
      bf16x8 b0 = ldB2(&xbf[(((kk2 * 8 + g2) * 16) + r) * 4],
                       &xbf[(((kk2 * 8 + 4 + g2) * 16) + r) * 4]);
      acc = __builtin_amdgcn_mfma_f32_16x16x32_bf16(a, b0, acc, 0, 0, 0);
    }
  }
#pragma unroll
  for (int p = 0; p < 4; p++) {
    int o = 16 * w + g2 * 4 + p;
    y[((size_t)b * D_ + o) * LC_ + l0 + r] = acc[p];
  }
}

// ---------------------------------------------------------------- host side

extern "C" void kernel_launch(void* const* d_in, const int* in_sizes, int n_in,
                              void* d_out, int out_size, void* d_ws, size_t ws_size,
                              hipStream_t stream) {
  (void)in_sizes; (void)n_in; (void)out_size; (void)ws_size;
  const float* C        = (const float*)d_in[0];
  const float* Q        = (const float*)d_in[1];
  const float* maskC    = (const float*)d_in[2];
  const float* maskQ    = (const float*)d_in[3];
  const float* e_dw     = (const float*)d_in[4];
  const float* e_pw     = (const float*)d_in[5];
  const float* e_pw_b   = (const float*)d_in[6];
  const float* e_lnc_g  = (const float*)d_in[7];
  const float* e_lnc_b  = (const float*)d_in[8];
  const float* e_mem_w  = (const float*)d_in[9];
  const float* e_q_w    = (const float*)d_in[10];
  const float* e_ffn1_w = (const float*)d_in[11];
  const float* e_ffn1_b = (const float*)d_in[12];
  const float* e_ffn2_w = (const float*)d_in[13];
  const float* e_ffn2_b = (const float*)d_in[14];
  const float* e_ln1_g  = (const float*)d_in[15];
  const float* e_ln1_b  = (const float*)d_in[16];
  const float* e_ln2_g  = (const float*)d_in[17];
  const float* e_ln2_b  = (const float*)d_in[18];
  const float* w4C      = (const float*)d_in[19];
  const float* w4Q      = (const float*)d_in[20];
  const float* w4mlu    = (const float*)d_in[21];
  const float* cq_b     = (const float*)d_in[22];
  const float* resizer_w= (const float*)d_in[23];
  const float* m_dw     = (const float*)d_in[24];
  const float* m_pw     = (const float*)d_in[25];
  const float* m_pw_b   = (const float*)d_in[26];
  const float* m_lnc_g  = (const float*)d_in[27];
  const float* m_lnc_b  = (const float*)d_in[28];
  const float* m_mem_w  = (const float*)d_in[29];
  const float* m_q_w    = (const float*)d_in[30];
  const float* m_ffn1_w = (const float*)d_in[31];
  const float* m_ffn1_b = (const float*)d_in[32];
  const float* m_ffn2_w = (const float*)d_in[33];
  const float* m_ffn2_b = (const float*)d_in[34];
  const float* m_ln1_g  = (const float*)d_in[35];
  const float* m_ln1_b  = (const float*)d_in[36];
  const float* m_ln2_g  = (const float*)d_in[37];
  const float* m_ln2_b  = (const float*)d_in[38];

  float* ws = (float*)d_ws;
  const size_t SB = (size_t)B_ * D_ * LC_;
  float* cur  = ws;
  float* aux  = cur + SB;
  float* mkvF = aux + SB;
  float* qpbF = mkvF + 2 * SB;
  float* Ce   = qpbF + SB;
  float* Qe   = Ce + 2 * SB;
  float* Sbuf = Qe + (size_t)B_ * 256 * LQ_;
  float* S1   = Sbuf + (size_t)B_ * LC_ * LQ_;
  float* S2   = S1 + (size_t)B_ * LC_ * LQ_;
  float* Yb   = S2 + (size_t)B_ * LC_ * LQ_;
  float* Mb   = Yb + (size_t)B_ * 256 * LQ_;
  float* Ab   = mkvF;
  float* Bb   = cur;
  ushortT* mkvB = (ushortT*)mkvF;
  ushortT* qpbB = (ushortT*)qpbF;
  ushortT* wb = (ushortT*)(Mb + SB);
  ushortT* w_epw  = wb;
  ushortT* w_emem = wb + 65536;
  ushortT* w_eq   = wb + 98304;
  ushortT* w_ef1  = wb + 114688;
  ushortT* w_ef2  = wb + 131072;
  ushortT* w_rsz  = wb + 147456;
  ushortT* w_mpw  = wb + 311296;
  ushortT* w_mmem = wb + 540672;
  ushortT* w_mq   = wb + 770048;
  ushortT* w_mf1  = wb + 884736;
  ushortT* w_mf2  = wb + 999424;
  float* after_wb = (float*)(wb + 1114112);
  float* curQ  = after_wb;
  float* auxQ  = curQ + 65536;
  ushortT* mkvQB = (ushortT*)(auxQ + 65536);
  ushortT* qpbQB = (ushortT*)(auxQ + 131072);
  float* posT  = auxQ + 196608;

  k_prep<<<(1114112 + 255) / 256, 256, 0, stream>>>(
      e_pw, e_mem_w, e_q_w, e_ffn1_w, e_ffn2_w, resizer_w,
      m_pw, m_mem_w, m_q_w, m_ffn1_w, m_ffn2_w, wb);
  k_postab<<<256, 256, 0, stream>>>(posT);

  // ---- merged C+Q input encoders ----
  k_fusedconv<7, 1><<<dim3(36, 2, B_), 256, 0, stream>>>(
      C, cur, Q, curQ, posT,
      e_dw + 0 * 896, w_epw + 0, e_pw_b + 0, e_lnc_g + 0, e_lnc_b + 0,
      e_dw + 1 * 896, w_epw + 16384, e_pw_b + 128, e_lnc_g + 128, e_lnc_b + 128, 32);
  k_convproj1024<7, 0><<<dim3(36, 1, B_), 1024, 0, stream>>>(
      cur, aux, mkvB, qpbB, curQ, auxQ, mkvQB, qpbQB, posT,
      e_dw + 2 * 896, w_epw + 32768, e_pw_b + 256, e_lnc_g + 256, e_lnc_b + 256,
      e_dw + 3 * 896, w_epw + 49152, e_pw_b + 384, e_lnc_g + 384, e_lnc_b + 384,
      w_emem, w_eq, e_ln1_g, e_ln1_b, 32);
  k_attnffn_in<<<dim3(36, 1, B_), 1024, 0, stream>>>(
      mkvB, qpbB, maskC, aux, mkvQB, qpbQB, maskQ, auxQ,
      w_ef1, e_ffn1_b, w_ef2, e_ffn2_b, e_ln2_g, e_ln2_b, 32);
  k_concat2m<<<(B_ * 256 * (LC_ + LQ_) + 255) / 256, 256, 0, stream>>>(
      aux, C, Ce, auxQ, Q, Qe);

  // ---- CQ attention + resizer -> Mb ----
  k_cqSrow<<<(B_ * LC_ * LQ_) / 256, 256, 0, stream>>>(Ce, Qe, w4C, w4Q, w4mlu, cq_b, maskQ, Sbuf, S1);
  k_softmax_col<<<B_ * LQ_, 256, 0, stream>>>(Sbuf, maskC, S2);
  k_cqY<<<(B_ * 256 * LQ_) / 256, 256, 0, stream>>>(S2, Ce, Yb);
  k_cqAB<<<dim3(LC_ / 64, 64, B_), 256, 0, stream>>>(S1, Qe, Yb, Ab, Bb);
  k_resizer512<<<dim3(LC_ / 16, 1, B_), 512, 0, stream>>>(Ce, Ab, Bb, w_rsz, Mb);

  // ---- model encoder: 3 runs of 7 blocks, ping-pong cur/aux ----
  float* out = (float*)d_out;
  float* bufs[2] = {cur, aux};
  int cb = 0;
  const float* src = Mb;
  for (int r = 0; r < 3; r++) {
    for (int bi = 0; bi < 7; bi++) {
      int pc0 = bi * 2, pc1 = bi * 2 + 1;
      float* ob = bufs[cb];
      k_fusedconv<5, 1><<<dim3(32, 2, B_), 256, 0, stream>>>(
          src, ob, src, ob, posT,
          m_dw + (size_t)pc0 * 640, w_mpw + (size_t)pc0 * 16384, m_pw_b + pc0 * 128,
          m_lnc_g + pc0 * 128, m_lnc_b + pc0 * 128,
          m_dw + (size_t)pc1 * 640, w_mpw + (size_t)pc1 * 16384, m_pw_b + pc1 * 128,
          m_lnc_g + pc1 * 128, m_lnc_b + pc1 * 128, 32);
      k_proj<<<dim3(32, 1, B_), 512, 0, stream>>>(
          ob, w_mmem + (size_t)bi * 32768, w_mq + (size_t)bi * 16384,
          m_ln1_g + bi * 128, m_ln1_b + bi * 128, mkvB, qpbB);
      if (bi == 6)
        k_attnffn_m<1><<<dim3(32, 1, B_), 1024, 0, stream>>>(
            mkvB, qpbB, maskC, ob,
            w_mf1 + (size_t)bi * 16384, m_ffn1_b + bi * 128,
            w_mf2 + (size_t)bi * 16384, m_ffn2_b + bi * 128,
            m_ln2_g + bi * 128, m_ln2_b + bi * 128, out + (size_t)r * SB);
      else
        k_attnffn_m<0><<<dim3(32, 1, B_), 1024, 0, stream>>>(
            mkvB, qpbB, maskC, ob,
            w_mf1 + (size_t)bi * 16384, m_ffn1_b + bi * 128,
            w_mf2 + (size_t)bi * 16384, m_ffn2_b + bi * 128,
            m_ln2_g + bi * 128, m_ln2_b + bi * 128, nullptr);
      src = ob;
      cb ^= 1;
    }
  }
}

// Round 16
// 1237.353 us; speedup vs baseline: 1.2260x; 1.2260x over previous
//
#include <hip/hip_runtime.h>
#include <math.h>

#define D_  128
#define B_  8
#define H_  8
#define LC_ 512
#define LQ_ 64

typedef float f32x4 __attribute__((ext_vector_type(4)));
typedef short bf16x8 __attribute__((ext_vector_type(8)));
typedef short short4v __attribute__((ext_vector_type(4)));
typedef unsigned short ushortT;

__device__ inline short bfr(float x) {
  unsigned u = __float_as_uint(x);
  u += 0x7fff + ((u >> 16) & 1);
  return (short)(u >> 16);
}
__device__ inline float bfi(ushortT u) {
  return __uint_as_float(((unsigned)u) << 16);
}

__device__ inline bf16x8 mk8(short4v lo, short4v hi) {
  bf16x8 r;
  r[0] = lo[0]; r[1] = lo[1]; r[2] = lo[2]; r[3] = lo[3];
  r[4] = hi[0]; r[5] = hi[1]; r[6] = hi[2]; r[7] = hi[3];
  return r;
}

// A-frag: W[m=lane&15][k], k = koff + g*4 + (j&3) + 16*(j>>2)
__device__ inline bf16x8 ldA(const ushortT* row, int koff) {
  short4v lo = *(const short4v*)(row + koff);
  short4v hi = *(const short4v*)(row + koff + 16);
  return mk8(lo, hi);
}
__device__ inline bf16x8 ldB2(const ushortT* plo, const ushortT* phi) {
  short4v lo = *(const short4v*)plo;
  short4v hi = *(const short4v*)phi;
  return mk8(lo, hi);
}

// ---------------------------------------------------------------- weight prep
__global__ void k_prep(const float* a0, const float* a1, const float* a2,
                       const float* a3, const float* a4, const float* a5,
                       const float* a6, const float* a7, const float* a8,
                       const float* a9, const float* a10, ushortT* dst) {
  int i = blockIdx.x * 256 + threadIdx.x;
  if (i >= 1114112) return;
  const float* s; int lo;
  if      (i <   65536) { s = a0;  lo = i; }
  else if (i <   98304) { s = a1;  lo = i - 65536; }
  else if (i <  114688) { s = a2;  lo = i - 98304; }
  else if (i <  131072) { s = a3;  lo = i - 114688; }
  else if (i <  147456) { s = a4;  lo = i - 131072; }
  else if (i <  311296) { s = a5;  lo = i - 147456; }
  else if (i <  540672) { s = a6;  lo = i - 311296; }
  else if (i <  770048) { s = a7;  lo = i - 540672; }
  else if (i <  884736) { s = a8;  lo = i - 770048; }
  else if (i <  999424) { s = a9;  lo = i - 884736; }
  else                  { s = a10; lo = i - 999424; }
  dst[i] = (ushortT)bfr(s[lo]);
}

// pos-signal table: pos[d*512 + l]
__global__ void k_postab(float* pos) {
  int i = blockIdx.x * 256 + threadIdx.x;  // 65536
  int d = i >> 9, l = i & 511;
  int j = d & 63;
  float arg = (float)l * expf(-(float)j * 0.14619588f);
  pos[i] = (d < 64) ? sinf(arg) : cosf(arg);
}

// ---------------------------------------------------------------- fused double conv (dual C/Q)
// grid (ntC + ntQ, 2, B), 256 thr; bx<ntC -> C tile, else Q tile.
template <int KK, int ADDPOS>
__global__ __launch_bounds__(256) void k_fusedconv(
    const float* __restrict__ xC, float* __restrict__ yC,
    const float* __restrict__ xQ, float* __restrict__ yQ,
    const float* __restrict__ pos,
    const float* __restrict__ dw1, const ushortT* __restrict__ pw1,
    const float* __restrict__ pb1, const float* __restrict__ g1,
    const float* __restrict__ be1,
    const float* __restrict__ dw2, const ushortT* __restrict__ pw2,
    const float* __restrict__ pb2, const float* __restrict__ g2w,
    const float* __restrict__ be2, int ntC) {
  const int HALO = KK / 2;
  const int W1 = 32 + 2 * HALO;
  __shared__ __align__(16) float raw[128 * 40];
  __shared__ __align__(16) ushortT l1o[128 * 36];
  __shared__ __align__(16) ushortT xbf1[32 * 32 * 4];
  __shared__ float mu1[40], rs1[40], mu2[32], rs2[32], ps[160], psq[160];
  ushortT* xbf2 = (ushortT*)raw;
  int bx = blockIdx.x;
  const float* x; float* yout; int l0, L;
  if (bx < ntC) { x = xC; yout = yC; l0 = bx * 16; L = LC_; }
  else          { x = xQ; yout = yQ; l0 = (bx - ntC) * 16; L = LQ_; }
  int o0 = blockIdx.y * 64;
  int b = blockIdx.z;
  int tid = threadIdx.x;
  for (int idx = tid; idx < 128 * W1; idx += 256) {
    int d = idx / W1, c = idx - d * W1;
    int gl = l0 - 8 - HALO + c;
    float v = 0.f;
    if (gl >= 0 && gl < L) {
      v = x[((size_t)b * 128 + d) * L + gl];
      if (ADDPOS) v += pos[d * 512 + gl];
    }
    raw[d * 40 + c] = v;
  }
  __syncthreads();
  if (tid < 4 * W1) {
    int c = tid % W1, hh = tid / W1;
    float s = 0.f, s2 = 0.f;
    for (int d = hh * 32; d < hh * 32 + 32; d++) {
      float v = raw[d * 40 + c];
      s += v; s2 += v * v;
    }
    ps[tid] = s; psq[tid] = s2;
  }
  __syncthreads();
  if (tid < W1) {
    float s = ps[tid] + ps[tid + W1] + ps[tid + 2 * W1] + ps[tid + 3 * W1];
    float s2 = psq[tid] + psq[tid + W1] + psq[tid + 2 * W1] + psq[tid + 3 * W1];
    float mu = s * (1.f / 128.f);
    float var = fmaxf(s2 * (1.f / 128.f) - mu * mu, 0.f);
    mu1[tid] = mu; rs1[tid] = rsqrtf(var + 1e-5f);
  }
  __syncthreads();
  {
    int cc0 = tid & 31, dbase = tid >> 5;
#pragma unroll
    for (int kq = 0; kq < 4; kq++) {
      short4v pk;
#pragma unroll
      for (int e = 0; e < 4; e++) {
        int d = dbase * 16 + kq * 4 + e;
        float gg = g1[d], bb = be1[d];
        const float* wr = dw1 + d * KK;
        float acc = 0.f;
#pragma unroll
        for (int t = 0; t < KK; t++) {
          int ci = cc0 + t;
          int gl = l0 - 8 - HALO + ci;
          float lv = 0.f;
          if (gl >= 0 && gl < L)
            lv = (raw[d * 40 + ci] - mu1[ci]) * rs1[ci] * gg + bb;
          acc += wr[t] * lv;
        }
        pk[e] = bfr(acc);
      }
      *(short4v*)&xbf1[(((dbase * 4 + kq) * 32) + cc0) * 4] = pk;
    }
  }
  __syncthreads();
  int w = tid >> 6, lane = tid & 63, g2 = lane >> 4, r = lane & 15;
  {
    f32x4 acc[2][2];
#pragma unroll
    for (int i = 0; i < 2; i++)
#pragma unroll
      for (int nt = 0; nt < 2; nt++) acc[i][nt] = (f32x4){0.f, 0.f, 0.f, 0.f};
#pragma unroll
    for (int i = 0; i < 2; i++) {
      const ushortT* arow = pw1 + (size_t)((2 * w + i) * 16 + r) * 128;
#pragma unroll
      for (int kk = 0; kk < 4; kk++) {
        bf16x8 a = ldA(arow, kk * 32 + g2 * 4);
#pragma unroll
        for (int nt = 0; nt < 2; nt++) {
          bf16x8 bb = ldB2(&xbf1[(((kk * 8 + g2) * 32) + nt * 16 + r) * 4],
                           &xbf1[(((kk * 8 + 4 + g2) * 32) + nt * 16 + r) * 4]);
          acc[i][nt] = __builtin_amdgcn_mfma_f32_16x16x32_bf16(a, bb, acc[i][nt], 0, 0, 0);
        }
      }
    }
#pragma unroll
    for (int i = 0; i < 2; i++)
#pragma unroll
      for (int nt = 0; nt < 2; nt++)
#pragma unroll
        for (int p = 0; p < 4; p++) {
          int o = (2 * w + i) * 16 + g2 * 4 + p;
          int c1 = nt * 16 + r;
          int gl = l0 - 8 + c1;
          float val = 0.f;
          if (gl >= 0 && gl < L)
            val = fmaxf(acc[i][nt][p] + pb1[o], 0.f) + raw[o * 40 + c1 + HALO];
          l1o[o * 36 + c1] = (ushortT)bfr(val);
        }
  }
  __syncthreads();
  if (tid < 128) {
    int c = tid & 31, hh = tid >> 5;
    float s = 0.f, s2 = 0.f;
    for (int d = hh * 32; d < hh * 32 + 32; d++) {
      float v = bfi(l1o[d * 36 + c]);
      s += v; s2 += v * v;
    }
    ps[tid] = s; psq[tid] = s2;
  }
  __syncthreads();
  if (tid < 32) {
    float s = ps[tid] + ps[tid + 32] + ps[tid + 64] + ps[tid + 96];
    float s2 = psq[tid] + psq[tid + 32] + psq[tid + 64] + psq[tid + 96];
    float mu = s * (1.f / 128.f);
    float var = fmaxf(s2 * (1.f / 128.f) - mu * mu, 0.f);
    mu2[tid] = mu; rs2[tid] = rsqrtf(var + 1e-5f);
  }
  __syncthreads();
  {
    int cc2 = tid & 15, db2 = tid >> 4;
#pragma unroll
    for (int kq = 0; kq < 2; kq++) {
      short4v pk;
#pragma unroll
      for (int e = 0; e < 4; e++) {
        int d = db2 * 8 + kq * 4 + e;
        float gg = g2w[d], bb = be2[d];
        const float* wr = dw2 + d * KK;
        float acc = 0.f;
#pragma unroll
        for (int t = 0; t < KK; t++) {
          int c1 = cc2 + 8 + t - HALO;
          int gl = l0 + cc2 + t - HALO;
          float lv = 0.f;
          if (gl >= 0 && gl < L)
            lv = (bfi(l1o[d * 36 + c1]) - mu2[c1]) * rs2[c1] * gg + bb;
          acc += wr[t] * lv;
        }
        pk[e] = bfr(acc);
      }
      *(short4v*)&xbf2[(((db2 * 2 + kq) * 16) + cc2) * 4] = pk;
    }
  }
  __syncthreads();
  {
    f32x4 a2 = {0.f, 0.f, 0.f, 0.f};
    const ushortT* arow = pw2 + (size_t)(o0 + 16 * w + r) * 128;
#pragma unroll
    for (int kk = 0; kk < 4; kk++) {
      bf16x8 a = ldA(arow, kk * 32 + g2 * 4);
      bf16x8 bb = ldB2(&xbf2[(((kk * 8 + g2) * 16) + r) * 4],
                       &xbf2[(((kk * 8 + 4 + g2) * 16) + r) * 4]);
      a2 = __builtin_amdgcn_mfma_f32_16x16x32_bf16(a, bb, a2, 0, 0, 0);
    }
#pragma unroll
    for (int p = 0; p < 4; p++) {
      int o = o0 + 16 * w + g2 * 4 + p;
      yout[((size_t)b * 128 + o) * L + l0 + r] =
          fmaxf(a2[p] + pb2[o], 0.f) + bfi(l1o[o * 36 + 8 + r]);
    }
  }
}

// ---------------------------------------------------------------- conv pair + LN1 + projections (dual C/Q, 1024 thr)
// Projections written as bf16 (attn consumes bf16 anyway -> bit-identical).
template <int KK, int ADDPOS>
__global__ __launch_bounds__(1024) void k_convproj1024(
    const float* __restrict__ xC, float* __restrict__ yC,
    ushortT* __restrict__ mkvC, ushortT* __restrict__ qpC,
    const float* __restrict__ xQ, float* __restrict__ yQ,
    ushortT* __restrict__ mkvQ, ushortT* __restrict__ qpQ,
    const float* __restrict__ pos,
    const float* __restrict__ dw1, const ushortT* __restrict__ pw1,
    const float* __restrict__ pb1, const float* __restrict__ g1,
    const float* __restrict__ be1,
    const float* __restrict__ dw2, const ushortT* __restrict__ pw2,
    const float* __restrict__ pb2, const float* __restrict__ g2w,
    const float* __restrict__ be2,
    const ushortT* __restrict__ memw, const ushortT* __restrict__ qw,
    const float* __restrict__ g3, const float* __restrict__ be3, int ntC) {
  const int HALO = KK / 2;
  const int W1 = 32 + 2 * HALO;
  __shared__ __align__(16) float raw[128 * 40];
  __shared__ __align__(16) ushortT l1o[128 * 36];
  __shared__ __align__(16) ushortT xbf1[32 * 32 * 4];
  __shared__ __align__(16) ushortT c2o[128 * 16];
  __shared__ float mu1[40], rs1[40], mu2[32], rs2[32], mu3[16], rs3[16];
  __shared__ float ps[160], psq[160];
  ushortT* xbf2 = (ushortT*)raw;
  ushortT* xbf3 = (ushortT*)(raw + 4096);
  int bx = blockIdx.x;
  const float* x; float* yout; ushortT* mkv; ushortT* qp; int l0, L;
  if (bx < ntC) { x = xC; yout = yC; mkv = mkvC; qp = qpC; l0 = bx * 16; L = LC_; }
  else          { x = xQ; yout = yQ; mkv = mkvQ; qp = qpQ; l0 = (bx - ntC) * 16; L = LQ_; }
  int b = blockIdx.z;
  int tid = threadIdx.x;
  for (int idx = tid; idx < 128 * W1; idx += 1024) {
    int d = idx / W1, c = idx - d * W1;
    int gl = l0 - 8 - HALO + c;
    float v = 0.f;
    if (gl >= 0 && gl < L) {
      v = x[((size_t)b * 128 + d) * L + gl];
      if (ADDPOS) v += pos[d * 512 + gl];
    }
    raw[d * 40 + c] = v;
  }
  __syncthreads();
  if (tid < 4 * W1) {
    int c = tid % W1, hh = tid / W1;
    float s = 0.f, s2 = 0.f;
    for (int d = hh * 32; d < hh * 32 + 32; d++) {
      float v = raw[d * 40 + c];
      s += v; s2 += v * v;
    }
    ps[tid] = s; psq[tid] = s2;
  }
  __syncthreads();
  if (tid < W1) {
    float s = ps[tid] + ps[tid + W1] + ps[tid + 2 * W1] + ps[tid + 3 * W1];
    float s2 = psq[tid] + psq[tid + W1] + psq[tid + 2 * W1] + psq[tid + 3 * W1];
    float mu = s * (1.f / 128.f);
    float var = fmaxf(s2 * (1.f / 128.f) - mu * mu, 0.f);
    mu1[tid] = mu; rs1[tid] = rsqrtf(var + 1e-5f);
  }
  __syncthreads();
  // dwconv1: 32 cols x 32 ch-groups (4 ch each)
  {
    int cc0 = tid & 31, dbase = tid >> 5;
    short4v pk;
#pragma unroll
    for (int e = 0; e < 4; e++) {
      int d = dbase * 4 + e;
      float gg = g1[d], bb = be1[d];
      const float* wr = dw1 + d * KK;
      float acc = 0.f;
#pragma unroll
      for (int t = 0; t < KK; t++) {
        int ci = cc0 + t;
        int gl = l0 - 8 - HALO + ci;
        float lv = 0.f;
        if (gl >= 0 && gl < L)
          lv = (raw[d * 40 + ci] - mu1[ci]) * rs1[ci] * gg + bb;
        acc += wr[t] * lv;
      }
      pk[e] = bfr(acc);
    }
    *(short4v*)&xbf1[((dbase * 32) + cc0) * 4] = pk;
  }
  __syncthreads();
  int w = tid >> 6, lane = tid & 63, g2 = lane >> 4, r = lane & 15;
  // GEMM1: 16 wave-tasks = (m = w&7, nt = w>>3)
  {
    int m = w & 7, nt = w >> 3;
    f32x4 acc = {0.f, 0.f, 0.f, 0.f};
    const ushortT* arow = pw1 + (size_t)(m * 16 + r) * 128;
#pragma unroll
    for (int kk = 0; kk < 4; kk++) {
      bf16x8 a = ldA(arow, kk * 32 + g2 * 4);
      bf16x8 bb = ldB2(&xbf1[(((kk * 8 + g2) * 32) + nt * 16 + r) * 4],
                       &xbf1[(((kk * 8 + 4 + g2) * 32) + nt * 16 + r) * 4]);
      acc = __builtin_amdgcn_mfma_f32_16x16x32_bf16(a, bb, acc, 0, 0, 0);
    }
#pragma unroll
    for (int p = 0; p < 4; p++) {
      int o = m * 16 + g2 * 4 + p;
      int c1 = nt * 16 + r;
      int gl = l0 - 8 + c1;
      float val = 0.f;
      if (gl >= 0 && gl < L)
        val = fmaxf(acc[p] + pb1[o], 0.f) + raw[o * 40 + c1 + HALO];
      l1o[o * 36 + c1] = (ushortT)bfr(val);
    }
  }
  __syncthreads();        // raw dead -> xbf2/xbf3 alias
  if (tid < 128) {
    int c = tid & 31, hh = tid >> 5;
    float s = 0.f, s2 = 0.f;
    for (int d = hh * 32; d < hh * 32 + 32; d++) {
      float v = bfi(l1o[d * 36 + c]);
      s += v; s2 += v * v;
    }
    ps[tid] = s; psq[tid] = s2;
  }
  __syncthreads();
  if (tid < 32) {
    float s = ps[tid] + ps[tid + 32] + ps[tid + 64] + ps[tid + 96];
    float s2 = psq[tid] + psq[tid + 32] + psq[tid + 64] + psq[tid + 96];
    float mu = s * (1.f / 128.f);
    float var = fmaxf(s2 * (1.f / 128.f) - mu * mu, 0.f);
    mu2[tid] = mu; rs2[tid] = rsqrtf(var + 1e-5f);
  }
  __syncthreads();
  // dwconv2: 16 cols x 64 ch-groups (2 ch each)
  {
    int cc2 = tid & 15, db2 = tid >> 4;
#pragma unroll
    for (int e = 0; e < 2; e++) {
      int d = db2 * 2 + e;
      float gg = g2w[d], bb = be2[d];
      const float* wr = dw2 + d * KK;
      float acc = 0.f;
#pragma unroll
      for (int t = 0; t < KK; t++) {
        int c1 = cc2 + 8 + t - HALO;
        int gl = l0 + cc2 + t - HALO;
        float lv = 0.f;
        if (gl >= 0 && gl < L)
          lv = (bfi(l1o[d * 36 + c1]) - mu2[c1]) * rs2[c1] * gg + bb;
        acc += wr[t] * lv;
      }
      xbf2[(((d >> 2) * 16) + cc2) * 4 + (d & 3)] = (ushortT)bfr(acc);
    }
  }
  __syncthreads();
  if (w < 8) {
    f32x4 a2 = {0.f, 0.f, 0.f, 0.f};
    const ushortT* arow = pw2 + (size_t)(w * 16 + r) * 128;
#pragma unroll
    for (int kk = 0; kk < 4; kk++) {
      bf16x8 a = ldA(arow, kk * 32 + g2 * 4);
      bf16x8 bb = ldB2(&xbf2[(((kk * 8 + g2) * 16) + r) * 4],
                       &xbf2[(((kk * 8 + 4 + g2) * 16) + r) * 4]);
      a2 = __builtin_amdgcn_mfma_f32_16x16x32_bf16(a, bb, a2, 0, 0, 0);
    }
#pragma unroll
    for (int p = 0; p < 4; p++) {
      int o = w * 16 + g2 * 4 + p;
      float val = fmaxf(a2[p] + pb2[o], 0.f) + bfi(l1o[o * 36 + 8 + r]);
      yout[((size_t)b * 128 + o) * L + l0 + r] = val;
      c2o[o * 16 + r] = (ushortT)bfr(val);
    }
  }
  __syncthreads();
  if (tid < 128) {
    int c = tid & 15, hh = tid >> 4;
    float s = 0.f, s2 = 0.f;
    for (int d = hh * 16; d < hh * 16 + 16; d++) {
      float v = bfi(c2o[d * 16 + c]);
      s += v; s2 += v * v;
    }
    ps[tid] = s; psq[tid] = s2;
  }
  __syncthreads();
  if (tid < 16) {
    float s = 0.f, s2 = 0.f;
#pragma unroll
    for (int hh = 0; hh < 8; hh++) { s += ps[hh * 16 + tid]; s2 += psq[hh * 16 + tid]; }
    float mu = s * (1.f / 128.f);
    float var = fmaxf(s2 * (1.f / 128.f) - mu * mu, 0.f);
    mu3[tid] = mu; rs3[tid] = rsqrtf(var + 1e-5f);
  }
  __syncthreads();
  for (int idx = tid; idx < 2048; idx += 1024) {
    int d = idx >> 4, c = idx & 15;
    float val = (bfi(c2o[d * 16 + c]) - mu3[c]) * rs3[c] * g3[d] + be3[d];
    xbf3[(((d >> 2) * 16) + c) * 4 + (d & 3)] = (ushortT)bfr(val);
  }
  __syncthreads();
#pragma unroll
  for (int t = 0; t < 2; t++) {
    int mt = w + 16 * t;
    if (mt < 24) {
      const ushortT* arow; ushortT* outp; int obase, O;
      if (mt < 16) { arow = memw + (size_t)(mt * 16 + r) * 128; outp = mkv; obase = mt * 16; O = 256; }
      else         { arow = qw + (size_t)((mt - 16) * 16 + r) * 128; outp = qp; obase = (mt - 16) * 16; O = 128; }
      f32x4 acc = {0.f, 0.f, 0.f, 0.f};
#pragma unroll
      for (int kk = 0; kk < 4; kk++) {
        bf16x8 a = ldA(arow, kk * 32 + g2 * 4);
        bf16x8 bb = ldB2(&xbf3[(((kk * 8 + g2) * 16) + r) * 4],
                         &xbf3[(((kk * 8 + 4 + g2) * 16) + r) * 4]);
        acc = __builtin_amdgcn_mfma_f32_16x16x32_bf16(a, bb, acc, 0, 0, 0);
      }
#pragma unroll
      for (int p = 0; p < 4; p++)
        outp[((size_t)b * O + obase + g2 * 4 + p) * L + l0 + r] = (ushortT)bfr(acc[p]);
    }
  }
}

// ---------------------------------------------------------------- attention + LN2 + FFN body (bf16 K/V/Q, 1024 thr)
template <int NCH, int WOUT>
__device__ __forceinline__ void attn_body(
    char* smem, const ushortT* memKV, const ushortT* qp, const float* mask,
    float* cur, const ushortT* w1bf, const float* b1,
    const ushortT* w2bf, const float* b2,
    const float* g, const float* be, float* wout, int q0, int b, int L, int tid) {
  float* msh = (float*)smem;
  float* ssh = (float*)(smem + 2048);
  float* OshF = (float*)(smem + 4096);
  float* updT = (float*)(smem + 12288);
  ushortT* xbf = (ushortT*)(smem + 20480);
  ushortT* midbf = (ushortT*)(smem + 24576);
  float* mu_s = (float*)(smem + 28672);
  float* rs_s = (float*)(smem + 28736);
  float* ps = (float*)(smem + 28800);
  float* psq = (float*)(smem + 32896);
  int w = tid >> 6;
  int h = w & 7, kh = w >> 3;
  int lane = tid & 63;
  int g2 = lane >> 4, r = lane & 15;
  const ushortT* qb = qp + ((size_t)b * 128 + h * 16) * L;
  const ushortT* kb = memKV + ((size_t)b * 256 + h * 16) * L;
  const ushortT* vb = memKV + ((size_t)b * 256 + 128 + h * 16) * L;
  const float* mk = mask + (size_t)b * L;
  int qcol = q0 + r;
  bf16x8 qf;
#pragma unroll
  for (int j = 0; j < 4; j++)
    qf[j] = bfr(bfi(qb[(size_t)(g2 * 4 + j) * L + qcol]) * 0.25f);
  qf[4] = 0; qf[5] = 0; qf[6] = 0; qf[7] = 0;
  float m_run = -INFINITY, ssum = 0.f;
  f32x4 O = {0.f, 0.f, 0.f, 0.f};
  int kbeg = kh * (L / 2), kend = (kh + 1) * (L / 2);
  for (int k0 = kbeg; k0 < kend; k0 += NCH * 16) {
    f32x4 sd[NCH];
#pragma unroll
    for (int mc = 0; mc < NCH; mc++) {
      bf16x8 kf;
      int krow = k0 + mc * 16 + r;
#pragma unroll
      for (int j = 0; j < 4; j++)
        kf[j] = (short)kb[(size_t)(g2 * 4 + j) * L + krow];
      kf[4] = 0; kf[5] = 0; kf[6] = 0; kf[7] = 0;
      f32x4 z = {0.f, 0.f, 0.f, 0.f};
      sd[mc] = __builtin_amdgcn_mfma_f32_16x16x32_bf16(kf, qf, z, 0, 0, 0);
    }
    float tm = -INFINITY;
#pragma unroll
    for (int mc = 0; mc < NCH; mc++) {
#pragma unroll
      for (int p = 0; p < 4; p++) {
        float mv = mk[k0 + mc * 16 + g2 * 4 + p];
        float sv = sd[mc][p] * mv + (1.f - mv) * (-1e30f);
        sd[mc][p] = sv;
        tm = fmaxf(tm, sv);
      }
    }
    tm = fmaxf(tm, __shfl_xor(tm, 16));
    tm = fmaxf(tm, __shfl_xor(tm, 32));
    float nm = fmaxf(m_run, tm);
    float c = __expf(m_run - nm);
    ssum *= c;
    O[0] *= c; O[1] *= c; O[2] *= c; O[3] *= c;
    float psum = 0.f;
    bf16x8 pf[NCH / 2];
#pragma unroll
    for (int c2 = 0; c2 < NCH / 2; c2++) {
#pragma unroll
      for (int j = 0; j < 4; j++) {
        float e0 = __expf(sd[2 * c2][j] - nm);
        float e1 = __expf(sd[2 * c2 + 1][j] - nm);
        psum += e0 + e1;
        pf[c2][j] = bfr(e0);
        pf[c2][j + 4] = bfr(e1);
      }
    }
    psum += __shfl_xor(psum, 16);
    psum += __shfl_xor(psum, 32);
    ssum += psum;
#pragma unroll
    for (int c2 = 0; c2 < NCH / 2; c2++) {
      const ushortT* vrow = vb + (size_t)r * L + k0 + c2 * 32 + g2 * 4;
      short4v lo = *(const short4v*)vrow;
      short4v hi = *(const short4v*)(vrow + 16);
      bf16x8 vf = mk8(lo, hi);
      O = __builtin_amdgcn_mfma_f32_16x16x32_bf16(vf, pf[c2], O, 0, 0, 0);
    }
    m_run = nm;
  }
  if (kh == 1) {
    msh[h * 64 + lane] = m_run;
    ssh[h * 64 + lane] = ssum;
#pragma unroll
    for (int p = 0; p < 4; p++) OshF[(h * 64 + lane) * 4 + p] = O[p];
  }
  __syncthreads();
  if (kh == 0) {
    float mB = msh[h * 64 + lane], sB = ssh[h * 64 + lane];
    float nm = fmaxf(m_run, mB);
    float cA = __expf(m_run - nm), cB = __expf(mB - nm);
    float inv = 1.f / (ssum * cA + sB * cB);
#pragma unroll
    for (int p = 0; p < 4; p++) {
      int d = h * 16 + g2 * 4 + p;
      float ov = (O[p] * cA + OshF[(h * 64 + lane) * 4 + p] * cB) * inv;
      updT[d * 16 + r] = cur[((size_t)b * 128 + d) * L + qcol] + ov;
    }
  }
  __syncthreads();
  {
    int c = tid & 15, hh = tid >> 4;
    float s = 0.f, s2 = 0.f;
    for (int d = hh * 2; d < hh * 2 + 2; d++) {
      float v = updT[d * 16 + c];
      s += v; s2 += v * v;
    }
    ps[tid] = s; psq[tid] = s2;
  }
  __syncthreads();
  if (tid < 16) {
    float s = 0.f, s2 = 0.f;
    for (int hh = 0; hh < 64; hh++) { s += ps[hh * 16 + tid]; s2 += psq[hh * 16 + tid]; }
    float mu = s * (1.f / 128.f);
    float var = fmaxf(s2 * (1.f / 128.f) - mu * mu, 0.f);
    mu_s[tid] = mu; rs_s[tid] = rsqrtf(var + 1e-5f);
  }
  __syncthreads();
  for (int idx = tid; idx < 2048; idx += 1024) {
    int d = idx >> 4, c = idx & 15;
    float val = (updT[d * 16 + c] - mu_s[c]) * rs_s[c] * g[d] + be[d];
    xbf[(((d >> 2) * 16) + c) * 4 + (d & 3)] = (ushortT)bfr(val);
  }
  __syncthreads();
  int w8 = tid >> 6;
  int g2b = (tid & 63) >> 4, rb = tid & 15;
  if (w8 < 8) {
    f32x4 acc = {0.f, 0.f, 0.f, 0.f};
    const ushortT* ar = w1bf + (size_t)(16 * w8 + rb) * 128;
#pragma unroll
    for (int kk = 0; kk < 4; kk++) {
      bf16x8 a = ldA(ar, kk * 32 + g2b * 4);
      bf16x8 bb = ldB2(&xbf[(((kk * 8 + g2b) * 16) + rb) * 4],
                       &xbf[(((kk * 8 + 4 + g2b) * 16) + rb) * 4]);
      acc = __builtin_amdgcn_mfma_f32_16x16x32_bf16(a, bb, acc, 0, 0, 0);
    }
#pragma unroll
    for (int p = 0; p < 4; p++) {
      int dmid = 16 * w8 + g2b * 4 + p;
      float val = fmaxf(acc[p] + b1[dmid], 0.f);
      midbf[(((4 * w8 + g2b) * 16) + rb) * 4 + p] = (ushortT)bfr(val);
    }
  }
  __syncthreads();
  if (w8 < 8) {
    f32x4 a2 = {0.f, 0.f, 0.f, 0.f};
    const ushortT* ar = w2bf + (size_t)(16 * w8 + rb) * 128;
#pragma unroll
    for (int kk = 0; kk < 4; kk++) {
      bf16x8 a = ldA(ar, kk * 32 + g2b * 4);
      bf16x8 bb = ldB2(&midbf[(((kk * 8 + g2b) * 16) + rb) * 4],
                       &midbf[(((kk * 8 + 4 + g2b) * 16) + rb) * 4]);
      a2 = __builtin_amdgcn_mfma_f32_16x16x32_bf16(a, bb, a2, 0, 0, 0);
    }
#pragma unroll
    for (int p = 0; p < 4; p++) {
      int o = 16 * w8 + g2b * 4 + p;
      size_t pos2 = ((size_t)b * 128 + o) * L + q0 + rb;
      float val = a2[p] + b2[o] + updT[o * 16 + rb];
      cur[pos2] = val;
      if (WOUT) wout[pos2] = val;
    }
  }
}

// model-encoder wrapper
template <int WOUT>
__global__ __launch_bounds__(1024) void k_attnffn_m(
    const ushortT* memKV, const ushortT* qp, const float* mask, float* cur,
    const ushortT* w1bf, const float* b1, const ushortT* w2bf, const float* b2,
    const float* g, const float* be, float* wout) {
  __shared__ __align__(16) char smem[36992];
  attn_body<8, WOUT>(smem, memKV, qp, mask, cur, w1bf, b1, w2bf, b2, g, be,
                     wout, blockIdx.x * 16, blockIdx.z, LC_, threadIdx.x);
}

// merged input-encoder wrapper
__global__ __launch_bounds__(1024) void k_attnffn_in(
    const ushortT* mkvC, const ushortT* qpC, const float* maskC, float* curC,
    const ushortT* mkvQ, const ushortT* qpQ, const float* maskQ, float* curQ,
    const ushortT* w1bf, const float* b1, const ushortT* w2bf, const float* b2,
    const float* g, const float* be, int ntC) {
  __shared__ __align__(16) char smem[36992];
  int bx = blockIdx.x;
  if (bx < ntC)
    attn_body<8, 0>(smem, mkvC, qpC, maskC, curC, w1bf, b1, w2bf, b2, g, be,
                    nullptr, bx * 16, blockIdx.z, LC_, threadIdx.x);
  else
    attn_body<2, 0>(smem, mkvQ, qpQ, maskQ, curQ, w1bf, b1, w2bf, b2, g, be,
                    nullptr, (bx - ntC) * 16, blockIdx.z, LQ_, threadIdx.x);
}

// ---------------------------------------------------------------- CQ section

__global__ void k_concat2m(const float* __restrict__ x1C, const float* __restrict__ x2C,
                           float* __restrict__ outC,
                           const float* __restrict__ x1Q, const float* __restrict__ x2Q,
                           float* __restrict__ outQ) {
  int idx = blockIdx.x * 256 + threadIdx.x;
  const int tot1 = B_ * 256 * LC_;
  const int tot2 = B_ * 256 * LQ_;
  if (idx < tot1) {
    int l = idx % LC_;
    int c = (idx / LC_) & 255;
    int b = idx / (LC_ * 256);
    float v = (c < 128) ? x1C[((size_t)b * 128 + c) * LC_ + l]
                        : x2C[((size_t)b * 128 + (c - 128)) * LC_ + l];
    outC[idx] = v;
  } else {
    int i2 = idx - tot1;
    if (i2 < tot2) {
      int l = i2 % LQ_;
      int c = (i2 / LQ_) & 255;
      int b = i2 / (LQ_ * 256);
      float v = (c < 128) ? x1Q[((size_t)b * 128 + c) * LQ_ + l]
                          : x2Q[((size_t)b * 128 + (c - 128)) * LQ_ + l];
      outQ[i2] = v;
    }
  }
}

__global__ void k_cqSrow(const float* __restrict__ Ce, const float* __restrict__ Qe,
                         const float* __restrict__ w4C, const float* __restrict__ w4Q,
                         const float* __restrict__ w4mlu, const float* __restrict__ cqb,
                         const float* __restrict__ qmask,
                         float* __restrict__ S, float* __restrict__ S1) {
  int idx = blockIdx.x * 256 + threadIdx.x;
  int q = idx & 63;
  int l = (idx >> 6) % LC_;
  int b = (idx >> 6) / LC_;
  const float* ce = Ce + (size_t)b * 256 * LC_ + l;
  const float* qe = Qe + (size_t)b * 256 * LQ_ + q;
  float acc = 0.f, a0 = 0.f, a1 = 0.f;
#pragma unroll 8
  for (int j = 0; j < 256; j++) {
    float cv = ce[(size_t)j * LC_];
    float qv = qe[(size_t)j * LQ_];
    acc += cv * w4mlu[j] * qv;
    a0 += cv * w4C[j];
    a1 += qv * w4Q[j];
  }
  float sv = acc + a0 + a1 + cqb[0];
  S[idx] = sv;
  float mv = qmask[b * LQ_ + q];
  float v = sv * mv + (1.f - mv) * (-1e30f);
  float mx = v;
  for (int off = 32; off; off >>= 1) mx = fmaxf(mx, __shfl_xor(mx, off));
  float p = expf(v - mx);
  float s = p;
  for (int off = 32; off; off >>= 1) s += __shfl_xor(s, off);
  S1[idx] = p / s;
}

__global__ __launch_bounds__(256) void k_softmax_col(
    const float* __restrict__ S, const float* __restrict__ cmask, float* __restrict__ S2) {
  int q = blockIdx.x & 63, b = blockIdx.x >> 6;
  int tid = threadIdx.x;
  __shared__ float redm[4], reds[4];
  const float* col = S + (size_t)b * LC_ * LQ_ + q;
  const float* mk = cmask + b * LC_;
  float vm[2];
#pragma unroll
  for (int k = 0; k < 2; k++) {
    int l = tid + 256 * k;
    float mv = mk[l];
    vm[k] = col[(size_t)l * LQ_] * mv + (1.f - mv) * (-1e30f);
  }
  float mx = fmaxf(vm[0], vm[1]);
  for (int off = 32; off; off >>= 1) mx = fmaxf(mx, __shfl_xor(mx, off));
  if ((tid & 63) == 0) redm[tid >> 6] = mx;
  __syncthreads();
  mx = fmaxf(fmaxf(redm[0], redm[1]), fmaxf(redm[2], redm[3]));
  float e0 = expf(vm[0] - mx), e1 = expf(vm[1] - mx);
  float s = e0 + e1;
  for (int off = 32; off; off >>= 1) s += __shfl_xor(s, off);
  if ((tid & 63) == 0) reds[tid >> 6] = s;
  __syncthreads();
  float invs = 1.f / (reds[0] + reds[1] + reds[2] + reds[3]);
  float* out = S2 + (size_t)b * LC_ * LQ_ + q;
  out[(size_t)tid * LQ_] = e0 * invs;
  out[(size_t)(tid + 256) * LQ_] = e1 * invs;
}

__global__ void k_cqY(const float* __restrict__ S2, const float* __restrict__ Ce,
                      float* __restrict__ Y) {
  int idx = blockIdx.x * 256 + threadIdx.x;
  if (idx >= B_ * 256 * LQ_) return;
  int q = idx & 63;
  int j = (idx >> 6) & 255;
  int b = idx >> 14;
  const float* s2 = S2 + (size_t)b * LC_ * LQ_ + q;
  const float* ce = Ce + ((size_t)b * 256 + j) * LC_;
  float acc = 0.f;
#pragma unroll 8
  for (int l = 0; l < LC_; l++) acc += s2[(size_t)l * LQ_] * ce[l];
  Y[idx] = acc;
}

__global__ __launch_bounds__(256) void k_cqAB(
    const float* __restrict__ S1, const float* __restrict__ Qe, const float* __restrict__ Y,
    float* __restrict__ A, float* __restrict__ Bt) {
  __shared__ float s1s[64][65];
  int l0 = blockIdx.x * 64;
  int b = blockIdx.z;
  int tid = threadIdx.x;
  for (int idx = tid; idx < 64 * 64; idx += 256) {
    int l = idx >> 6, q = idx & 63;
    s1s[l][q] = S1[((size_t)b * LC_ + l0 + l) * LQ_ + q];
  }
  __syncthreads();
  int ll = tid & 63, jj = tid >> 6;
  int j = blockIdx.y * 4 + jj;
  const float* qe = Qe + ((size_t)b * 256 + j) * LQ_;
  const float* yb = Y + ((size_t)b * 256 + j) * LQ_;
  float a = 0.f, bt = 0.f;
#pragma unroll 8
  for (int q = 0; q < 64; q++) {
    float sv = s1s[ll][q];
    a += sv * qe[q];
    bt += sv * yb[q];
  }
  A[((size_t)b * 256 + j) * LC_ + l0 + ll] = a;
  Bt[((size_t)b * 256 + j) * LC_ + l0 + ll] = bt;
}

__global__ __launch_bounds__(512) void k_resizer512(
    const float* __restrict__ Ce, const float* __restrict__ A,
    const float* __restrict__ Bt, const ushortT* __restrict__ wbf,
    float* __restrict__ y) {
  __shared__ __align__(16) ushortT xbf[32 * 16 * 4];
  int l0 = blockIdx.x * 16;
  int b = blockIdx.z;
  int tid = threadIdx.x;
  int w = tid >> 6, lane = tid & 63, g2 = lane >> 4, r = lane & 15;
  const ushortT* arow = wbf + (size_t)(16 * w + r) * 1280;
  f32x4 acc = {0.f, 0.f, 0.f, 0.f};
  for (int kt = 0; kt < 1280; kt += 128) {
    __syncthreads();
    for (int idx = tid; idx < 2048; idx += 512) {
      int kl = idx >> 4, cc = idx & 15;
      int ch = kt + kl;
      int seg = ch >> 8;
      int j = ch & 255;
      size_t p = ((size_t)b * 256 + j) * LC_ + l0 + cc;
      float v;
      if (seg == 0 || seg == 4) v = Ce[p];
      else if (seg == 1) v = A[p];
      else if (seg == 2) v = Ce[p] * A[p];
      else v = Ce[p] * Bt[p];
      xbf[((kl >> 2) * 16 + cc) * 4 + (kl & 3)] = (ushortT)bfr(v);
    }
    __syncthreads();
#pragma unroll
    for (int kk2 = 0; kk2 < 4; kk2++) {
      bf16x8 a = ldA(arow, kt + kk2 * 32 + g2 * 4);
      bf16x8 b0 = ldB2(&xbf[(((kk2 * 8 + g2) * 16) + r) * 4],
                       &xbf[(((kk2 * 8 + 4 + g2) * 16) + r) * 4]);
      acc = __builtin_amdgcn_mfma_f32_16x16x32_bf16(a, b0, acc, 0, 0, 0);
    }
  }
#pragma unroll
  for (int p = 0; p < 4; p++) {
    int o = 16 * w + g2 * 4 + p;
    y[((size_t)b * D_ + o) * LC_ + l0 + r] = acc[p];
  }
}

// ---------------------------------------------------------------- host side

extern "C" void kernel_launch(void* const* d_in, const int* in_sizes, int n_in,
                              void* d_out, int out_size, void* d_ws, size_t ws_size,
                              hipStream_t stream) {
  (void)in_sizes; (void)n_in; (void)out_size; (void)ws_size;
  const float* C        = (const float*)d_in[0];
  const float* Q        = (const float*)d_in[1];
  const float* maskC    = (const float*)d_in[2];
  const float* maskQ    = (const float*)d_in[3];
  const float* e_dw     = (const float*)d_in[4];
  const float* e_pw     = (const float*)d_in[5];
  const float* e_pw_b   = (const float*)d_in[6];
  const float* e_lnc_g  = (const float*)d_in[7];
  const float* e_lnc_b  = (const float*)d_in[8];
  const float* e_mem_w  = (const float*)d_in[9];
  const float* e_q_w    = (const float*)d_in[10];
  const float* e_ffn1_w = (const float*)d_in[11];
  const float* e_ffn1_b = (const float*)d_in[12];
  const float* e_ffn2_w = (const float*)d_in[13];
  const float* e_ffn2_b = (const float*)d_in[14];
  const float* e_ln1_g  = (const float*)d_in[15];
  const float* e_ln1_b  = (const float*)d_in[16];
  const float* e_ln2_g  = (const float*)d_in[17];
  const float* e_ln2_b  = (const float*)d_in[18];
  const float* w4C      = (const float*)d_in[19];
  const float* w4Q      = (const float*)d_in[20];
  const float* w4mlu    = (const float*)d_in[21];
  const float* cq_b     = (const float*)d_in[22];
  const float* resizer_w= (const float*)d_in[23];
  const float* m_dw     = (const float*)d_in[24];
  const float* m_pw     = (const float*)d_in[25];
  const float* m_pw_b   = (const float*)d_in[26];
  const float* m_lnc_g  = (const float*)d_in[27];
  const float* m_lnc_b  = (const float*)d_in[28];
  const float* m_mem_w  = (const float*)d_in[29];
  const float* m_q_w    = (const float*)d_in[30];
  const float* m_ffn1_w = (const float*)d_in[31];
  const float* m_ffn1_b = (const float*)d_in[32];
  const float* m_ffn2_w = (const float*)d_in[33];
  const float* m_ffn2_b = (const float*)d_in[34];
  const float* m_ln1_g  = (const float*)d_in[35];
  const float* m_ln1_b  = (const float*)d_in[36];
  const float* m_ln2_g  = (const float*)d_in[37];
  const float* m_ln2_b  = (const float*)d_in[38];

  float* ws = (float*)d_ws;
  const size_t SB = (size_t)B_ * D_ * LC_;
  float* cur  = ws;
  float* aux  = cur + SB;
  float* mkvF = aux + SB;          // region 2*SB floats; used as bf16 (half)
  float* qpbF = mkvF + 2 * SB;     // region SB floats; used as bf16
  float* Ce   = qpbF + SB;
  float* Qe   = Ce + 2 * SB;
  float* Sbuf = Qe + (size_t)B_ * 256 * LQ_;
  float* S1   = Sbuf + (size_t)B_ * LC_ * LQ_;
  float* S2   = S1 + (size_t)B_ * LC_ * LQ_;
  float* Yb   = S2 + (size_t)B_ * LC_ * LQ_;
  float* Mb   = Yb + (size_t)B_ * 256 * LQ_;
  float* Ab   = mkvF;              // alias: free during CQ section (fp32 ok)
  float* Bb   = cur;
  ushortT* mkvB = (ushortT*)mkvF;
  ushortT* qpbB = (ushortT*)qpbF;
  ushortT* wb = (ushortT*)(Mb + SB);
  ushortT* w_epw  = wb;
  ushortT* w_emem = wb + 65536;
  ushortT* w_eq   = wb + 98304;
  ushortT* w_ef1  = wb + 114688;
  ushortT* w_ef2  = wb + 131072;
  ushortT* w_rsz  = wb + 147456;
  ushortT* w_mpw  = wb + 311296;
  ushortT* w_mmem = wb + 540672;
  ushortT* w_mq   = wb + 770048;
  ushortT* w_mf1  = wb + 884736;
  ushortT* w_mf2  = wb + 999424;
  float* after_wb = (float*)(wb + 1114112);
  float* curQ  = after_wb;                    // 65536 floats
  float* auxQ  = curQ + 65536;                // 65536
  ushortT* mkvQB = (ushortT*)(auxQ + 65536);  // 131072 ushorts = 65536 floats
  ushortT* qpbQB = (ushortT*)(auxQ + 131072); // 65536 ushorts
  float* posT  = auxQ + 196608;               // 65536 floats

  k_prep<<<(1114112 + 255) / 256, 256, 0, stream>>>(
      e_pw, e_mem_w, e_q_w, e_ffn1_w, e_ffn2_w, resizer_w,
      m_pw, m_mem_w, m_q_w, m_ffn1_w, m_ffn2_w, wb);
  k_postab<<<256, 256, 0, stream>>>(posT);

  // ---- merged C+Q input encoders ----
  k_fusedconv<7, 1><<<dim3(36, 2, B_), 256, 0, stream>>>(
      C, cur, Q, curQ, posT,
      e_dw + 0 * 896, w_epw + 0, e_pw_b + 0, e_lnc_g + 0, e_lnc_b + 0,
      e_dw + 1 * 896, w_epw + 16384, e_pw_b + 128, e_lnc_g + 128, e_lnc_b + 128, 32);
  k_convproj1024<7, 0><<<dim3(36, 1, B_), 1024, 0, stream>>>(
      cur, aux, mkvB, qpbB, curQ, auxQ, mkvQB, qpbQB, posT,
      e_dw + 2 * 896, w_epw + 32768, e_pw_b + 256, e_lnc_g + 256, e_lnc_b + 256,
      e_dw + 3 * 896, w_epw + 49152, e_pw_b + 384, e_lnc_g + 384, e_lnc_b + 384,
      w_emem, w_eq, e_ln1_g, e_ln1_b, 32);
  k_attnffn_in<<<dim3(36, 1, B_), 1024, 0, stream>>>(
      mkvB, qpbB, maskC, aux, mkvQB, qpbQB, maskQ, auxQ,
      w_ef1, e_ffn1_b, w_ef2, e_ffn2_b, e_ln2_g, e_ln2_b, 32);
  k_concat2m<<<(B_ * 256 * (LC_ + LQ_) + 255) / 256, 256, 0, stream>>>(
      aux, C, Ce, auxQ, Q, Qe);

  // ---- CQ attention + resizer -> Mb ----
  k_cqSrow<<<(B_ * LC_ * LQ_) / 256, 256, 0, stream>>>(Ce, Qe, w4C, w4Q, w4mlu, cq_b, maskQ, Sbuf, S1);
  k_softmax_col<<<B_ * LQ_, 256, 0, stream>>>(Sbuf, maskC, S2);
  k_cqY<<<(B_ * 256 * LQ_) / 256, 256, 0, stream>>>(S2, Ce, Yb);
  k_cqAB<<<dim3(LC_ / 64, 64, B_), 256, 0, stream>>>(S1, Qe, Yb, Ab, Bb);
  k_resizer512<<<dim3(LC_ / 16, 1, B_), 512, 0, stream>>>(Ce, Ab, Bb, w_rsz, Mb);

  // ---- model encoder: 3 runs of 7 blocks, ping-pong cur/aux ----
  float* out = (float*)d_out;
  float* bufs[2] = {cur, aux};
  int cb = 0;
  const float* src = Mb;
  for (int r = 0; r < 3; r++) {
    for (int bi = 0; bi < 7; bi++) {
      int pc0 = bi * 2, pc1 = bi * 2 + 1;
      float* ob = bufs[cb];
      k_convproj1024<5, 1><<<dim3(32, 1, B_), 1024, 0, stream>>>(
          src, ob, mkvB, qpbB, src, ob, mkvB, qpbB, posT,
          m_dw + (size_t)pc0 * 640, w_mpw + (size_t)pc0 * 16384, m_pw_b + pc0 * 128,
          m_lnc_g + pc0 * 128, m_lnc_b + pc0 * 128,
          m_dw + (size_t)pc1 * 640, w_mpw + (size_t)pc1 * 16384, m_pw_b + pc1 * 128,
          m_lnc_g + pc1 * 128, m_lnc_b + pc1 * 128,
          w_mmem + (size_t)bi * 32768, w_mq + (size_t)bi * 16384,
          m_ln1_g + bi * 128, m_ln1_b + bi * 128, 32);
      if (bi == 6)
        k_attnffn_m<1><<<dim3(32, 1, B_), 1024, 0, stream>>>(
            mkvB, qpbB, maskC, ob,
            w_mf1 + (size_t)bi * 16384, m_ffn1_b + bi * 128,
            w_mf2 + (size_t)bi * 16384, m_ffn2_b + bi * 128,
            m_ln2_g + bi * 128, m_ln2_b + bi * 128, out + (size_t)r * SB);
      else
        k_attnffn_m<0><<<dim3(32, 1, B_), 1024, 0, stream>>>(
            mkvB, qpbB, maskC, ob,
            w_mf1 + (size_t)bi * 16384, m_ffn1_b + bi * 128,
            w_mf2 + (size_t)bi * 16384, m_ffn2_b + bi * 128,
            m_ln2_g + bi * 128, m_ln2_b + bi * 128, nullptr);
      src = ob;
      cb ^= 1;
    }
  }
}